// Round 2
// baseline (354.506 us; speedup 1.0000x reference)
//
#include <hip/hip_runtime.h>

// B=4, S=2048, D=1024, H=16, HS=64. Full bf16-MFMA pipeline.
// Workspace layout (needs ~104 MiB):
//   Xb     @ 0         : x as bf16            [8192][1024]   16 MiB
//   WqkvT  @ 16777216  : qkv weights B^T bf16 [3072][1024]    6 MiB
//   WoT    @ 23068672  : Wo^T bf16            [1024][1024]    2 MiB
//   QKV    @ 25165824  : Q|K|V bf16           [8192][3072]   48 MiB
//   VT     @ 75497472  : V^T bf16             [64bh][64][2048] 16 MiB
//   AttnO  @ 92274688  : attention out bf16   [8192][1024]   16 MiB

typedef __bf16 bf16;
typedef bf16 bf16x8 __attribute__((ext_vector_type(8)));
typedef bf16 bf16x4 __attribute__((ext_vector_type(4)));
typedef float f32x4 __attribute__((ext_vector_type(4)));

__device__ __forceinline__ void gload16(const void* gsrc, void* ldst) {
  __builtin_amdgcn_global_load_lds(
      (const __attribute__((address_space(1))) unsigned int*)gsrc,
      (__attribute__((address_space(3))) unsigned int*)ldst, 16, 0, 0);
}

__device__ __forceinline__ f32x4 mfma16(bf16x8 a, bf16x8 b, f32x4 c) {
  return __builtin_amdgcn_mfma_f32_16x16x32_bf16(a, b, c, 0, 0, 0);
}

// ---------------- pack kernels ----------------
__global__ __launch_bounds__(256) void pack_x_kernel(const float* __restrict__ x,
                                                     bf16* __restrict__ xb) {
  int i = (blockIdx.x * 256 + threadIdx.x) * 4;  // grid sized exactly
  float4 v = *(const float4*)(x + i);
  bf16x4 o;
  o[0] = (bf16)v.x; o[1] = (bf16)v.y; o[2] = (bf16)v.z; o[3] = (bf16)v.w;
  *(bf16x4*)(xb + i) = o;
}

// WT[n][k] = W{q,k,v}[h = (n%1024)/64][k][e = n%64], n in [0,3072)
__global__ __launch_bounds__(256) void pack_wqkv_kernel(const float* __restrict__ Wq,
                                                        const float* __restrict__ Wk,
                                                        const float* __restrict__ Wv,
                                                        bf16* __restrict__ WT) {
  int idx = blockIdx.x * 256 + threadIdx.x;  // 0..3145727
  int n = idx >> 10, k = idx & 1023;
  int sel = n >> 10, nn = n & 1023;
  const float* W = (sel == 0) ? Wq : (sel == 1 ? Wk : Wv);
  int h = nn >> 6, e = nn & 63;
  WT[(size_t)n * 1024 + k] = (bf16)W[h * 65536 + k * 64 + e];
}

// WoT[n][k] = Wo[k][n]
__global__ __launch_bounds__(256) void pack_wo_kernel(const float* __restrict__ Wo,
                                                      bf16* __restrict__ WoT) {
  int idx = blockIdx.x * 256 + threadIdx.x;  // 0..1048575
  int n = idx >> 10, k = idx & 1023;
  WoT[idx] = (bf16)Wo[k * 1024 + n];
}

// ---------------- GEMM: C[M][N] = A[M][K] * BT[N][K]^T ----------------
// 128x128 tile, BK=32, 4 waves (2x2), each wave 64x64 (4x4 frags of 16x16x32).
template <bool F32OUT>
__global__ __launch_bounds__(256) void gemm_bt_kernel(const bf16* __restrict__ A,
                                                      const bf16* __restrict__ BT,
                                                      bf16* __restrict__ Cb,
                                                      float* __restrict__ Cf,
                                                      const float* __restrict__ bias,
                                                      int M, int N, int K) {
  __shared__ bf16 As[128 * 32];
  __shared__ bf16 Bs[128 * 32];
  const int tid = threadIdx.x, lane = tid & 63, wave = tid >> 6;
  const int g = lane >> 4, c = lane & 15;
  // bijective XCD swizzle (grid sizes are multiples of 8)
  const int nx = gridDim.x;
  const int nwg = nx * gridDim.y;
  const int bid = blockIdx.y * nx + blockIdx.x;
  const int swz = (bid & 7) * (nwg >> 3) + (bid >> 3);
  const int m0 = (swz / nx) * 128, n0 = (swz % nx) * 128;
  const int wr = wave >> 1, wc = wave & 1;

  f32x4 acc[4][4] = {};
  for (int k0 = 0; k0 < K; k0 += 32) {
#pragma unroll
    for (int t = 0; t < 2; ++t) {
      int o = t * 4096 + wave * 1024 + lane * 16;  // byte offset in 8KB tile
      int row = o >> 6, kb = (o & 63) >> 1;        // row, k-elem within BK
      gload16(A + (size_t)(m0 + row) * K + k0 + kb, (char*)As + o);
      gload16(BT + (size_t)(n0 + row) * K + k0 + kb, (char*)Bs + o);
    }
    __syncthreads();
    bf16x8 af[4], bfr[4];
#pragma unroll
    for (int m = 0; m < 4; ++m)
      af[m] = *(const bf16x8*)((const char*)As + (wr * 64 + m * 16 + c) * 64 + g * 16);
#pragma unroll
    for (int n = 0; n < 4; ++n)
      bfr[n] = *(const bf16x8*)((const char*)Bs + (wc * 64 + n * 16 + c) * 64 + g * 16);
#pragma unroll
    for (int m = 0; m < 4; ++m)
#pragma unroll
      for (int n = 0; n < 4; ++n)
        acc[m][n] = mfma16(af[m], bfr[n], acc[m][n]);
    __syncthreads();
  }
#pragma unroll
  for (int m = 0; m < 4; ++m)
#pragma unroll
    for (int n = 0; n < 4; ++n)
#pragma unroll
      for (int i = 0; i < 4; ++i) {
        int row = m0 + wr * 64 + m * 16 + g * 4 + i;
        int col = n0 + wc * 64 + n * 16 + c;
        if (F32OUT)
          Cf[(size_t)row * N + col] = acc[m][n][i] + bias[col];
        else
          Cb[(size_t)row * N + col] = (bf16)acc[m][n][i];
      }
}

// ---------------- V transpose: VT[bh][d][s] = V[b,s,h,d] ----------------
// 64x64 tile per block; 512 bf16x8 chunks per side -> 2 iterations per thread.
__global__ __launch_bounds__(256) void transpose_v_kernel(const bf16* __restrict__ qkv,
                                                          bf16* __restrict__ vt) {
  __shared__ bf16 tl[64][72];  // stride 144B keeps 16B alignment for b128 stores
  const int tid = threadIdx.x;
  const int st = blockIdx.x, bh = blockIdx.y;
  const int b = bh >> 4, h = bh & 15;
#pragma unroll
  for (int it = 0; it < 2; ++it) {
    int idx = it * 256 + tid;          // 0..511
    int sl = idx >> 3, ch = idx & 7;   // sl 0..63 (s row), ch 0..7 (d chunk)
    bf16x8 v = *(const bf16x8*)(qkv + (size_t)(b * 2048 + st * 64 + sl) * 3072 + 2048 + h * 64 + ch * 8);
    *(bf16x8*)&tl[sl][ch * 8] = v;
  }
  __syncthreads();
#pragma unroll
  for (int it = 0; it < 2; ++it) {
    int idx = it * 256 + tid;
    int d = idx >> 3, s8 = idx & 7;    // d 0..63, s chunk 0..7
    bf16x8 o;
#pragma unroll
    for (int j = 0; j < 8; ++j) o[j] = tl[s8 * 8 + j][d];
    *(bf16x8*)(vt + ((size_t)bh * 64 + d) * 2048 + st * 64 + s8 * 8) = o;
  }
}

// ---------------- causal flash attention ----------------
// grid (16 qtiles, 64 bh), 256 threads = 4 waves, 32 q-rows/wave, K-tiles of 64.
__global__ __launch_bounds__(256) void attn_kernel(const bf16* __restrict__ qkv,
                                                   const bf16* __restrict__ vt,
                                                   bf16* __restrict__ attn_out) {
  __shared__ bf16 Ks[64 * 64];       // [key][hd], chunk-swizzled
  __shared__ bf16 Vs[64 * 64];       // [d][key], chunk-swizzled
  __shared__ bf16 Ps[4][32 * 72];    // per-wave P, padded rows (144B stride)
  const int tid = threadIdx.x, lane = tid & 63, wave = tid >> 6;
  const int g = lane >> 4, c = lane & 15;
  const int qt = blockIdx.x, bh = blockIdx.y;
  const int b = bh >> 4, h = bh & 15;

  bf16x8 qf[2][2];
#pragma unroll
  for (int m = 0; m < 2; ++m)
#pragma unroll
    for (int kk = 0; kk < 2; ++kk) {
      size_t row = (size_t)(b * 2048 + qt * 128 + wave * 32 + m * 16 + c);
      qf[m][kk] = *(const bf16x8*)(qkv + row * 3072 + h * 64 + kk * 32 + g * 8);
    }

  f32x4 oacc[2][4] = {};
  float mrun[2][4], lrun[2][4];
#pragma unroll
  for (int m = 0; m < 2; ++m)
#pragma unroll
    for (int i = 0; i < 4; ++i) { mrun[m][i] = -3.0e38f; lrun[m][i] = 0.f; }

  const int nkt = 2 * qt + 2;
  const int qmaxw = qt * 128 + wave * 32 + 31;
  for (int kt = 0; kt < nkt; ++kt) {
    // stage K tile and V^T tile (linear LDS dest, pre-swizzled global source)
#pragma unroll
    for (int t = 0; t < 2; ++t) {
      int o = t * 4096 + wave * 1024 + lane * 16;
      int r = o >> 7, ch = (o & 127) >> 4;
      int chs = ch ^ (r & 7);
      gload16((const char*)qkv + ((size_t)(b * 2048 + kt * 64 + r) * 3072 + 1024 + h * 64) * 2 + (chs << 4),
              (char*)Ks + o);
      gload16((const char*)vt + (((size_t)bh * 64 + r) * 2048 + kt * 64) * 2 + (chs << 4),
              (char*)Vs + o);
    }
    __syncthreads();
    if (kt * 64 <= qmaxw) {  // wave-uniform: skip fully-masked tiles
      f32x4 sc[2][4] = {};
#pragma unroll
      for (int n = 0; n < 4; ++n) {
        int key = n * 16 + c;
#pragma unroll
        for (int kk = 0; kk < 2; ++kk) {
          bf16x8 kf = *(const bf16x8*)((const char*)Ks + key * 128 + (((kk * 4 + g) ^ (key & 7)) << 4));
#pragma unroll
          for (int m = 0; m < 2; ++m) sc[m][n] = mfma16(qf[m][kk], kf, sc[m][n]);
        }
      }
      // online softmax (fp32)
#pragma unroll
      for (int m = 0; m < 2; ++m)
#pragma unroll
        for (int i = 0; i < 4; ++i) {
          int q = qt * 128 + wave * 32 + m * 16 + 4 * g + i;
          float vmax = -3.0e38f;
#pragma unroll
          for (int n = 0; n < 4; ++n) {
            float s = sc[m][n][i] * 0.125f;
            s = ((kt * 64 + n * 16 + c) <= q) ? s : -3.0e38f;
            sc[m][n][i] = s;
            vmax = fmaxf(vmax, s);
          }
          vmax = fmaxf(vmax, __shfl_xor(vmax, 1));
          vmax = fmaxf(vmax, __shfl_xor(vmax, 2));
          vmax = fmaxf(vmax, __shfl_xor(vmax, 4));
          vmax = fmaxf(vmax, __shfl_xor(vmax, 8));
          float mnew = fmaxf(mrun[m][i], vmax);
          float fs = __expf(mrun[m][i] - mnew);
          mrun[m][i] = mnew;
          float rs = 0.f;
#pragma unroll
          for (int n = 0; n < 4; ++n) {
            float p = __expf(sc[m][n][i] - mnew);
            sc[m][n][i] = p;
            rs += p;
          }
          rs += __shfl_xor(rs, 1);
          rs += __shfl_xor(rs, 2);
          rs += __shfl_xor(rs, 4);
          rs += __shfl_xor(rs, 8);
          lrun[m][i] = lrun[m][i] * fs + rs;
#pragma unroll
          for (int dn = 0; dn < 4; ++dn) oacc[m][dn][i] *= fs;
        }
      // P -> LDS (bf16), per-wave private region
#pragma unroll
      for (int m = 0; m < 2; ++m)
#pragma unroll
        for (int n = 0; n < 4; ++n)
#pragma unroll
          for (int i = 0; i < 4; ++i)
            Ps[wave][(m * 16 + 4 * g + i) * 72 + n * 16 + c] = (bf16)sc[m][n][i];
      asm volatile("s_waitcnt lgkmcnt(0)" ::: "memory");
      // PV
#pragma unroll
      for (int kk = 0; kk < 2; ++kk) {
        bf16x8 vf[4];
#pragma unroll
        for (int dn = 0; dn < 4; ++dn) {
          int d = dn * 16 + c;
          vf[dn] = *(const bf16x8*)((const char*)Vs + d * 128 + ((((kk * 4 + g) ^ (d & 7))) << 4));
        }
#pragma unroll
        for (int m = 0; m < 2; ++m) {
          bf16x8 pf = *(const bf16x8*)((const char*)&Ps[wave][0] + (m * 16 + c) * 144 + kk * 64 + g * 16);
#pragma unroll
          for (int dn = 0; dn < 4; ++dn) oacc[m][dn] = mfma16(pf, vf[dn], oacc[m][dn]);
        }
      }
    }
    __syncthreads();
  }
  // epilogue: normalize, store bf16 [8192][1024]
#pragma unroll
  for (int m = 0; m < 2; ++m)
#pragma unroll
    for (int i = 0; i < 4; ++i) {
      float inv = 1.0f / lrun[m][i];
      size_t row = (size_t)(b * 2048 + qt * 128 + wave * 32 + m * 16 + 4 * g + i);
#pragma unroll
      for (int dn = 0; dn < 4; ++dn)
        attn_out[row * 1024 + h * 64 + dn * 16 + c] = (bf16)(oacc[m][dn][i] * inv);
    }
}

// ---------------- launch ----------------
extern "C" void kernel_launch(void* const* d_in, const int* in_sizes, int n_in,
                              void* d_out, int out_size, void* d_ws, size_t ws_size,
                              hipStream_t stream) {
  const float* x  = (const float*)d_in[0];
  const float* Wq = (const float*)d_in[1];
  const float* Wk = (const float*)d_in[2];
  const float* Wv = (const float*)d_in[3];
  const float* Wo = (const float*)d_in[4];
  const float* bo = (const float*)d_in[5];
  float* out = (float*)d_out;
  char* ws = (char*)d_ws;

  bf16* Xb    = (bf16*)(ws);
  bf16* WqkvT = (bf16*)(ws + 16777216);
  bf16* WoT   = (bf16*)(ws + 23068672);
  bf16* QKV   = (bf16*)(ws + 25165824);
  bf16* VT    = (bf16*)(ws + 75497472);
  bf16* AttnO = (bf16*)(ws + 92274688);

  pack_x_kernel<<<8192, 256, 0, stream>>>(x, Xb);
  pack_wqkv_kernel<<<12288, 256, 0, stream>>>(Wq, Wk, Wv, WqkvT);
  pack_wo_kernel<<<4096, 256, 0, stream>>>(Wo, WoT);
  gemm_bt_kernel<false><<<dim3(24, 64), 256, 0, stream>>>(Xb, WqkvT, QKV, nullptr, nullptr,
                                                          8192, 3072, 1024);
  transpose_v_kernel<<<dim3(32, 64), 256, 0, stream>>>(QKV, VT);
  attn_kernel<<<dim3(16, 64), 256, 0, stream>>>(QKV, VT, AttnO);
  gemm_bt_kernel<true><<<dim3(8, 64), 256, 0, stream>>>(AttnO, WoT, nullptr, out, bo,
                                                        8192, 1024, 1024);
}

// Round 3
// 339.099 us; speedup vs baseline: 1.0454x; 1.0454x over previous
//
#include <hip/hip_runtime.h>

// B=4, S=2048, D=1024, H=16, HS=64. Full bf16-MFMA pipeline.
// Workspace layout (needs ~104 MiB):
//   Xb     @ 0         : x as bf16            [8192][1024]   16 MiB
//   WqkvT  @ 16777216  : qkv weights B^T bf16 [3072][1024]    6 MiB
//   WoT    @ 23068672  : Wo^T bf16            [1024][1024]    2 MiB
//   QKV    @ 25165824  : Q|K|V bf16           [8192][3072]   48 MiB
//   VT     @ 75497472  : V^T bf16             [64bh][64][2048] 16 MiB
//   AttnO  @ 92274688  : attention out bf16   [8192][1024]   16 MiB

typedef __bf16 bf16;
typedef bf16 bf16x8 __attribute__((ext_vector_type(8)));
typedef bf16 bf16x4 __attribute__((ext_vector_type(4)));
typedef float f32x4 __attribute__((ext_vector_type(4)));

__device__ __forceinline__ void gload16(const void* gsrc, void* ldst) {
  __builtin_amdgcn_global_load_lds(
      (const __attribute__((address_space(1))) unsigned int*)gsrc,
      (__attribute__((address_space(3))) unsigned int*)ldst, 16, 0, 0);
}

__device__ __forceinline__ f32x4 mfma16(bf16x8 a, bf16x8 b, f32x4 c) {
  return __builtin_amdgcn_mfma_f32_16x16x32_bf16(a, b, c, 0, 0, 0);
}

// ---------------- pack kernels ----------------
__global__ __launch_bounds__(256) void pack_x_kernel(const float* __restrict__ x,
                                                     bf16* __restrict__ xb) {
  int i = (blockIdx.x * 256 + threadIdx.x) * 4;  // grid sized exactly
  float4 v = *(const float4*)(x + i);
  bf16x4 o;
  o[0] = (bf16)v.x; o[1] = (bf16)v.y; o[2] = (bf16)v.z; o[3] = (bf16)v.w;
  *(bf16x4*)(xb + i) = o;
}

// WT[n][k] = W{q,k,v}[h = (n%1024)/64][k][e = n%64], n in [0,3072)
__global__ __launch_bounds__(256) void pack_wqkv_kernel(const float* __restrict__ Wq,
                                                        const float* __restrict__ Wk,
                                                        const float* __restrict__ Wv,
                                                        bf16* __restrict__ WT) {
  int idx = blockIdx.x * 256 + threadIdx.x;  // 0..3145727
  int n = idx >> 10, k = idx & 1023;
  int sel = n >> 10, nn = n & 1023;
  const float* W = (sel == 0) ? Wq : (sel == 1 ? Wk : Wv);
  int h = nn >> 6, e = nn & 63;
  WT[(size_t)n * 1024 + k] = (bf16)W[h * 65536 + k * 64 + e];
}

// WoT[n][k] = Wo[k][n]
__global__ __launch_bounds__(256) void pack_wo_kernel(const float* __restrict__ Wo,
                                                      bf16* __restrict__ WoT) {
  int idx = blockIdx.x * 256 + threadIdx.x;  // 0..1048575
  int n = idx >> 10, k = idx & 1023;
  WoT[idx] = (bf16)Wo[k * 1024 + n];
}

// ---------------- GEMM: C[M][N] = A[M][K] * BT[N][K]^T ----------------
// 128x128 tile, BK=32, 4 waves (2x2), each wave 64x64 (4x4 frags of 16x16x32).
template <bool F32OUT>
__global__ __launch_bounds__(256) void gemm_bt_kernel(const bf16* __restrict__ A,
                                                      const bf16* __restrict__ BT,
                                                      bf16* __restrict__ Cb,
                                                      float* __restrict__ Cf,
                                                      const float* __restrict__ bias,
                                                      int M, int N, int K) {
  __shared__ bf16 As[128 * 32];
  __shared__ bf16 Bs[128 * 32];
  const int tid = threadIdx.x, lane = tid & 63, wave = tid >> 6;
  const int g = lane >> 4, c = lane & 15;
  // bijective XCD swizzle (grid sizes are multiples of 8)
  const int nx = gridDim.x;
  const int nwg = nx * gridDim.y;
  const int bid = blockIdx.y * nx + blockIdx.x;
  const int swz = (bid & 7) * (nwg >> 3) + (bid >> 3);
  const int m0 = (swz / nx) * 128, n0 = (swz % nx) * 128;
  const int wr = wave >> 1, wc = wave & 1;

  f32x4 acc[4][4] = {};
  for (int k0 = 0; k0 < K; k0 += 32) {
#pragma unroll
    for (int t = 0; t < 2; ++t) {
      int o = t * 4096 + wave * 1024 + lane * 16;  // byte offset in 8KB tile
      int row = o >> 6, kb = (o & 63) >> 1;        // row, k-elem within BK
      gload16(A + (size_t)(m0 + row) * K + k0 + kb, (char*)As + o);
      gload16(BT + (size_t)(n0 + row) * K + k0 + kb, (char*)Bs + o);
    }
    __syncthreads();
    bf16x8 af[4], bfr[4];
#pragma unroll
    for (int m = 0; m < 4; ++m)
      af[m] = *(const bf16x8*)((const char*)As + (wr * 64 + m * 16 + c) * 64 + g * 16);
#pragma unroll
    for (int n = 0; n < 4; ++n)
      bfr[n] = *(const bf16x8*)((const char*)Bs + (wc * 64 + n * 16 + c) * 64 + g * 16);
#pragma unroll
    for (int m = 0; m < 4; ++m)
#pragma unroll
      for (int n = 0; n < 4; ++n)
        acc[m][n] = mfma16(af[m], bfr[n], acc[m][n]);
    __syncthreads();
  }
#pragma unroll
  for (int m = 0; m < 4; ++m)
#pragma unroll
    for (int n = 0; n < 4; ++n)
#pragma unroll
      for (int i = 0; i < 4; ++i) {
        int row = m0 + wr * 64 + m * 16 + g * 4 + i;
        int col = n0 + wc * 64 + n * 16 + c;
        if (F32OUT)
          Cf[(size_t)row * N + col] = acc[m][n][i] + bias[col];
        else
          Cb[(size_t)row * N + col] = (bf16)acc[m][n][i];
      }
}

// ---------------- V transpose: VT[bh][d][s] = V[b,s,h,d] ----------------
// 64x64 tile per block; 512 bf16x8 chunks per side -> 2 iterations per thread.
__global__ __launch_bounds__(256) void transpose_v_kernel(const bf16* __restrict__ qkv,
                                                          bf16* __restrict__ vt) {
  __shared__ bf16 tl[64][72];  // stride 144B keeps 16B alignment for b128 stores
  const int tid = threadIdx.x;
  const int st = blockIdx.x, bh = blockIdx.y;
  const int b = bh >> 4, h = bh & 15;
#pragma unroll
  for (int it = 0; it < 2; ++it) {
    int idx = it * 256 + tid;          // 0..511
    int sl = idx >> 3, ch = idx & 7;   // sl 0..63 (s row), ch 0..7 (d chunk)
    bf16x8 v = *(const bf16x8*)(qkv + (size_t)(b * 2048 + st * 64 + sl) * 3072 + 2048 + h * 64 + ch * 8);
    *(bf16x8*)&tl[sl][ch * 8] = v;
  }
  __syncthreads();
#pragma unroll
  for (int it = 0; it < 2; ++it) {
    int idx = it * 256 + tid;
    int d = idx >> 3, s8 = idx & 7;    // d 0..63, s chunk 0..7
    bf16x8 o;
#pragma unroll
    for (int j = 0; j < 8; ++j) o[j] = tl[s8 * 8 + j][d];
    *(bf16x8*)(vt + ((size_t)bh * 64 + d) * 2048 + st * 64 + s8 * 8) = o;
  }
}

// ---------------- causal flash attention ----------------
// grid (16 qtiles LPT-reversed, 64 bh), 256 threads = 4 waves, 32 q-rows/wave.
// K-tiles of 64, double-buffered staging with counted vmcnt + raw barriers.
__global__ __launch_bounds__(256) void attn_kernel(const bf16* __restrict__ qkv,
                                                   const bf16* __restrict__ vt,
                                                   bf16* __restrict__ attn_out) {
  __shared__ bf16 Ks[2][64 * 64];    // [key][hd], chunk-swizzled
  __shared__ bf16 Vs[2][64 * 64];    // [d][key], chunk-swizzled
  __shared__ bf16 Ps[4][32 * 72];    // per-wave P, padded rows (144B stride)
  const int tid = threadIdx.x, lane = tid & 63, wave = tid >> 6;
  const int g = lane >> 4, c = lane & 15;
  const int qt = 15 - (int)blockIdx.x;  // LPT: longest blocks dispatch first
  const int bh = blockIdx.y;
  const int b = bh >> 4, h = bh & 15;
  const float SCL = 0.125f * 1.4426950408889634f;  // log2(e) * scale

  bf16x8 qf[2][2];
#pragma unroll
  for (int m = 0; m < 2; ++m)
#pragma unroll
    for (int kk = 0; kk < 2; ++kk) {
      size_t row = (size_t)(b * 2048 + qt * 128 + wave * 32 + m * 16 + c);
      qf[m][kk] = *(const bf16x8*)(qkv + row * 3072 + h * 64 + kk * 32 + g * 8);
    }
  bf16x8 ones;
#pragma unroll
  for (int j = 0; j < 8; ++j) ones[j] = (bf16)1.0f;

  f32x4 oacc[2][4] = {};
  f32x4 lacc[2] = {};
  float mrun[2][4];
#pragma unroll
  for (int m = 0; m < 2; ++m)
#pragma unroll
    for (int i = 0; i < 4; ++i) mrun[m][i] = -3.0e38f;

  const int nkt = 2 * qt + 2;
  const int qlow = qt * 128 + wave * 32;  // lowest q row of this wave

#define STAGE(KT, BUF)                                                                     \
  do {                                                                                     \
    _Pragma("unroll") for (int t = 0; t < 2; ++t) {                                        \
      int o = t * 4096 + wave * 1024 + lane * 16;                                          \
      int r = o >> 7, chs = ((o & 127) >> 4) ^ (r & 7);                                    \
      gload16((const char*)qkv +                                                           \
                  ((size_t)(b * 2048 + (KT)*64 + r) * 3072 + 1024 + h * 64) * 2 +          \
                  (chs << 4),                                                              \
              (char*)Ks[BUF] + o);                                                         \
      gload16((const char*)vt + (((size_t)bh * 64 + r) * 2048 + (KT)*64) * 2 + (chs << 4), \
              (char*)Vs[BUF] + o);                                                         \
    }                                                                                      \
  } while (0)

  STAGE(0, 0);  // prologue
  for (int kt = 0; kt < nkt; ++kt) {
    const int cur = kt & 1;
    if (kt + 1 < nkt) {
      STAGE(kt + 1, cur ^ 1);
      asm volatile("s_waitcnt vmcnt(4)" ::: "memory");  // current tile landed
    } else {
      asm volatile("s_waitcnt vmcnt(0)" ::: "memory");
    }
    __builtin_amdgcn_sched_barrier(0);
    __builtin_amdgcn_s_barrier();
    __builtin_amdgcn_sched_barrier(0);
    if (kt * 64 <= qlow + 31) {  // wave-uniform: skip fully-masked tiles
      f32x4 sc[2][4] = {};
      __builtin_amdgcn_s_setprio(1);
#pragma unroll
      for (int n = 0; n < 4; ++n) {
        int key = n * 16 + c;
#pragma unroll
        for (int kk = 0; kk < 2; ++kk) {
          bf16x8 kf = *(const bf16x8*)((const char*)Ks[cur] + key * 128 +
                                       (((kk * 4 + g) ^ (key & 7)) << 4));
#pragma unroll
          for (int m = 0; m < 2; ++m) sc[m][n] = mfma16(qf[m][kk], kf, sc[m][n]);
        }
      }
      __builtin_amdgcn_s_setprio(0);
      // online softmax in exp2 domain; mask only on diagonal tiles
      const bool domask = (kt * 64 + 63) > qlow;
#pragma unroll
      for (int m = 0; m < 2; ++m)
#pragma unroll
        for (int i = 0; i < 4; ++i) {
          const int q = qlow + m * 16 + 4 * g + i;
          float vmax = -3.0e38f;
#pragma unroll
          for (int n = 0; n < 4; ++n) {
            float s = sc[m][n][i];
            if (domask) s = ((kt * 64 + n * 16 + c) <= q) ? s : -3.0e38f;
            sc[m][n][i] = s;
            vmax = fmaxf(vmax, s);
          }
          vmax = fmaxf(vmax, __shfl_xor(vmax, 1));
          vmax = fmaxf(vmax, __shfl_xor(vmax, 2));
          vmax = fmaxf(vmax, __shfl_xor(vmax, 4));
          vmax = fmaxf(vmax, __shfl_xor(vmax, 8));
          const float mnew = fmaxf(mrun[m][i], vmax * SCL);
          const float fs = __builtin_amdgcn_exp2f(mrun[m][i] - mnew);
          mrun[m][i] = mnew;
#pragma unroll
          for (int n = 0; n < 4; ++n) {
            float p = __builtin_amdgcn_exp2f(fmaf(sc[m][n][i], SCL, -mnew));
            Ps[wave][(m * 16 + 4 * g + i) * 72 + n * 16 + c] = (bf16)p;
          }
          lacc[m][i] *= fs;
#pragma unroll
          for (int dn = 0; dn < 4; ++dn) oacc[m][dn][i] *= fs;
        }
      asm volatile("s_waitcnt lgkmcnt(0)" ::: "memory");
      __builtin_amdgcn_sched_barrier(0);
      // PV + row-sum (l) via MFMA against ones
      __builtin_amdgcn_s_setprio(1);
#pragma unroll
      for (int kk = 0; kk < 2; ++kk) {
        bf16x8 vf[4];
#pragma unroll
        for (int dn = 0; dn < 4; ++dn) {
          int d = dn * 16 + c;
          vf[dn] = *(const bf16x8*)((const char*)Vs[cur] + d * 128 +
                                    (((kk * 4 + g) ^ (d & 7)) << 4));
        }
#pragma unroll
        for (int m = 0; m < 2; ++m) {
          bf16x8 pf = *(const bf16x8*)((const char*)Ps[wave] + (m * 16 + c) * 144 +
                                       kk * 64 + g * 16);
          lacc[m] = mfma16(pf, ones, lacc[m]);
#pragma unroll
          for (int dn = 0; dn < 4; ++dn) oacc[m][dn] = mfma16(pf, vf[dn], oacc[m][dn]);
        }
      }
      __builtin_amdgcn_s_setprio(0);
    }
    __builtin_amdgcn_sched_barrier(0);
    __builtin_amdgcn_s_barrier();  // readers done before next-tile overwrite
    __builtin_amdgcn_sched_barrier(0);
  }
#undef STAGE
  // epilogue: normalize, store bf16 [8192][1024]
#pragma unroll
  for (int m = 0; m < 2; ++m)
#pragma unroll
    for (int i = 0; i < 4; ++i) {
      float inv = __builtin_amdgcn_rcpf(lacc[m][i]);
      size_t row = (size_t)(b * 2048 + qt * 128 + wave * 32 + m * 16 + 4 * g + i);
#pragma unroll
      for (int dn = 0; dn < 4; ++dn)
        attn_out[row * 1024 + h * 64 + dn * 16 + c] = (bf16)(oacc[m][dn][i] * inv);
    }
}

// ---------------- launch ----------------
extern "C" void kernel_launch(void* const* d_in, const int* in_sizes, int n_in,
                              void* d_out, int out_size, void* d_ws, size_t ws_size,
                              hipStream_t stream) {
  const float* x  = (const float*)d_in[0];
  const float* Wq = (const float*)d_in[1];
  const float* Wk = (const float*)d_in[2];
  const float* Wv = (const float*)d_in[3];
  const float* Wo = (const float*)d_in[4];
  const float* bo = (const float*)d_in[5];
  float* out = (float*)d_out;
  char* ws = (char*)d_ws;

  bf16* Xb    = (bf16*)(ws);
  bf16* WqkvT = (bf16*)(ws + 16777216);
  bf16* WoT   = (bf16*)(ws + 23068672);
  bf16* QKV   = (bf16*)(ws + 25165824);
  bf16* VT    = (bf16*)(ws + 75497472);
  bf16* AttnO = (bf16*)(ws + 92274688);

  pack_x_kernel<<<8192, 256, 0, stream>>>(x, Xb);
  pack_wqkv_kernel<<<12288, 256, 0, stream>>>(Wq, Wk, Wv, WqkvT);
  pack_wo_kernel<<<4096, 256, 0, stream>>>(Wo, WoT);
  gemm_bt_kernel<false><<<dim3(24, 64), 256, 0, stream>>>(Xb, WqkvT, QKV, nullptr, nullptr,
                                                          8192, 3072, 1024);
  transpose_v_kernel<<<dim3(32, 64), 256, 0, stream>>>(QKV, VT);
  attn_kernel<<<dim3(16, 64), 256, 0, stream>>>(QKV, VT, AttnO);
  gemm_bt_kernel<true><<<dim3(8, 64), 256, 0, stream>>>(AttnO, WoT, nullptr, out, bo,
                                                        8192, 1024, 1024);
}

// Round 4
// 285.789 us; speedup vs baseline: 1.2404x; 1.1865x over previous
//
#include <hip/hip_runtime.h>

// B=4, S=2048, D=1024, H=16, HS=64. Full bf16-MFMA pipeline.
// Workspace layout (needs ~104 MiB):
//   Xb     @ 0         : x as bf16            [8192][1024]   16 MiB
//   WqkvT  @ 16777216  : qkv weights B^T bf16 [3072][1024]    6 MiB
//   WoT    @ 23068672  : Wo^T bf16            [1024][1024]    2 MiB
//   QKV    @ 25165824  : Q|K|V bf16           [8192][3072]   48 MiB
//   VT     @ 75497472  : V^T bf16             [64bh][64][2048] 16 MiB
//   AttnO  @ 92274688  : attention out bf16   [8192][1024]   16 MiB

typedef __bf16 bf16;
typedef bf16 bf16x8 __attribute__((ext_vector_type(8)));
typedef bf16 bf16x4 __attribute__((ext_vector_type(4)));
typedef float f32x4 __attribute__((ext_vector_type(4)));

__device__ __forceinline__ void gload16(const void* gsrc, void* ldst) {
  __builtin_amdgcn_global_load_lds(
      (const __attribute__((address_space(1))) unsigned int*)gsrc,
      (__attribute__((address_space(3))) unsigned int*)ldst, 16, 0, 0);
}

__device__ __forceinline__ f32x4 mfma16(bf16x8 a, bf16x8 b, f32x4 c) {
  return __builtin_amdgcn_mfma_f32_16x16x32_bf16(a, b, c, 0, 0, 0);
}

// ---------------- pack kernels ----------------
__global__ __launch_bounds__(256) void pack_x_kernel(const float* __restrict__ x,
                                                     bf16* __restrict__ xb) {
  int i = (blockIdx.x * 256 + threadIdx.x) * 4;  // grid sized exactly
  float4 v = *(const float4*)(x + i);
  bf16x4 o;
  o[0] = (bf16)v.x; o[1] = (bf16)v.y; o[2] = (bf16)v.z; o[3] = (bf16)v.w;
  *(bf16x4*)(xb + i) = o;
}

// WT[n][k] = W{q,k,v}[h = (n%1024)/64][k][e = n%64], n in [0,3072)
__global__ __launch_bounds__(256) void pack_wqkv_kernel(const float* __restrict__ Wq,
                                                        const float* __restrict__ Wk,
                                                        const float* __restrict__ Wv,
                                                        bf16* __restrict__ WT) {
  int idx = blockIdx.x * 256 + threadIdx.x;  // 0..3145727
  int n = idx >> 10, k = idx & 1023;
  int sel = n >> 10, nn = n & 1023;
  const float* W = (sel == 0) ? Wq : (sel == 1 ? Wk : Wv);
  int h = nn >> 6, e = nn & 63;
  WT[(size_t)n * 1024 + k] = (bf16)W[h * 65536 + k * 64 + e];
}

// WoT[n][k] = Wo[k][n]
__global__ __launch_bounds__(256) void pack_wo_kernel(const float* __restrict__ Wo,
                                                      bf16* __restrict__ WoT) {
  int idx = blockIdx.x * 256 + threadIdx.x;  // 0..1048575
  int n = idx >> 10, k = idx & 1023;
  WoT[idx] = (bf16)Wo[k * 1024 + n];
}

// ---------------- GEMM: C[M][N] = A[M][K] * BT[N][K]^T ----------------
// 128x128 tile, BK=32, 4 waves (2x2), each wave 64x64 (4x4 frags of 16x16x32).
template <bool F32OUT>
__global__ __launch_bounds__(256) void gemm_bt_kernel(const bf16* __restrict__ A,
                                                      const bf16* __restrict__ BT,
                                                      bf16* __restrict__ Cb,
                                                      float* __restrict__ Cf,
                                                      const float* __restrict__ bias,
                                                      int M, int N, int K) {
  __shared__ bf16 As[128 * 32];
  __shared__ bf16 Bs[128 * 32];
  const int tid = threadIdx.x, lane = tid & 63, wave = tid >> 6;
  const int g = lane >> 4, c = lane & 15;
  // bijective XCD swizzle (grid sizes are multiples of 8)
  const int nx = gridDim.x;
  const int nwg = nx * gridDim.y;
  const int bid = blockIdx.y * nx + blockIdx.x;
  const int swz = (bid & 7) * (nwg >> 3) + (bid >> 3);
  const int m0 = (swz / nx) * 128, n0 = (swz % nx) * 128;
  const int wr = wave >> 1, wc = wave & 1;

  f32x4 acc[4][4] = {};
  for (int k0 = 0; k0 < K; k0 += 32) {
#pragma unroll
    for (int t = 0; t < 2; ++t) {
      int o = t * 4096 + wave * 1024 + lane * 16;  // byte offset in 8KB tile
      int row = o >> 6, kb = (o & 63) >> 1;        // row, k-elem within BK
      gload16(A + (size_t)(m0 + row) * K + k0 + kb, (char*)As + o);
      gload16(BT + (size_t)(n0 + row) * K + k0 + kb, (char*)Bs + o);
    }
    __syncthreads();
    bf16x8 af[4], bfr[4];
#pragma unroll
    for (int m = 0; m < 4; ++m)
      af[m] = *(const bf16x8*)((const char*)As + (wr * 64 + m * 16 + c) * 64 + g * 16);
#pragma unroll
    for (int n = 0; n < 4; ++n)
      bfr[n] = *(const bf16x8*)((const char*)Bs + (wc * 64 + n * 16 + c) * 64 + g * 16);
#pragma unroll
    for (int m = 0; m < 4; ++m)
#pragma unroll
      for (int n = 0; n < 4; ++n)
        acc[m][n] = mfma16(af[m], bfr[n], acc[m][n]);
    __syncthreads();
  }
#pragma unroll
  for (int m = 0; m < 4; ++m)
#pragma unroll
    for (int n = 0; n < 4; ++n)
#pragma unroll
      for (int i = 0; i < 4; ++i) {
        int row = m0 + wr * 64 + m * 16 + g * 4 + i;
        int col = n0 + wc * 64 + n * 16 + c;
        if (F32OUT)
          Cf[(size_t)row * N + col] = acc[m][n][i] + bias[col];
        else
          Cb[(size_t)row * N + col] = (bf16)acc[m][n][i];
      }
}

// ---------------- V transpose: VT[bh][d][s] = V[b,s,h,d] ----------------
// 64x64 tile per block; 512 bf16x8 chunks per side -> 2 iterations per thread.
__global__ __launch_bounds__(256) void transpose_v_kernel(const bf16* __restrict__ qkv,
                                                          bf16* __restrict__ vt) {
  __shared__ bf16 tl[64][72];  // stride 144B keeps 16B alignment for b128 stores
  const int tid = threadIdx.x;
  const int st = blockIdx.x, bh = blockIdx.y;
  const int b = bh >> 4, h = bh & 15;
#pragma unroll
  for (int it = 0; it < 2; ++it) {
    int idx = it * 256 + tid;          // 0..511
    int sl = idx >> 3, ch = idx & 7;   // sl 0..63 (s row), ch 0..7 (d chunk)
    bf16x8 v = *(const bf16x8*)(qkv + (size_t)(b * 2048 + st * 64 + sl) * 3072 + 2048 + h * 64 + ch * 8);
    *(bf16x8*)&tl[sl][ch * 8] = v;
  }
  __syncthreads();
#pragma unroll
  for (int it = 0; it < 2; ++it) {
    int idx = it * 256 + tid;
    int d = idx >> 3, s8 = idx & 7;    // d 0..63, s chunk 0..7
    bf16x8 o;
#pragma unroll
    for (int j = 0; j < 8; ++j) o[j] = tl[s8 * 8 + j][d];
    *(bf16x8*)(vt + ((size_t)bh * 64 + d) * 2048 + st * 64 + s8 * 8) = o;
  }
}

// ---------------- causal flash attention ----------------
// 1D grid of 1024 blocks. Work-balance mapping: x = bid&15, bh = bid>>4,
// qt = ((bh>>4)&1) ? 15-x : x. Any stride-256 (or contiguous-16) set of
// blocks then carries a balanced qt mix -> every CU gets ~68 K-tiles total,
// fixing the 4-identical-blocks-per-CU imbalance of the dim3(16,64) grid.
// 256 threads = 4 waves, 32 q-rows/wave, K-tiles of 64, double-buffered
// staging with counted vmcnt + raw barriers.
__global__ __launch_bounds__(256) void attn_kernel(const bf16* __restrict__ qkv,
                                                   const bf16* __restrict__ vt,
                                                   bf16* __restrict__ attn_out) {
  __shared__ bf16 Ks[2][64 * 64];    // [key][hd], chunk-swizzled
  __shared__ bf16 Vs[2][64 * 64];    // [d][key], chunk-swizzled
  __shared__ bf16 Ps[4][32 * 72];    // per-wave P, padded rows (144B stride)
  const int tid = threadIdx.x, lane = tid & 63, wave = tid >> 6;
  const int g = lane >> 4, c = lane & 15;
  const int bid = blockIdx.x;
  const int x = bid & 15;
  const int bh = bid >> 4;
  const int qt = ((bh >> 4) & 1) ? (15 - x) : x;
  const int b = bh >> 4, h = bh & 15;
  const float SCL = 0.125f * 1.4426950408889634f;  // log2(e) * scale

  bf16x8 qf[2][2];
#pragma unroll
  for (int m = 0; m < 2; ++m)
#pragma unroll
    for (int kk = 0; kk < 2; ++kk) {
      size_t row = (size_t)(b * 2048 + qt * 128 + wave * 32 + m * 16 + c);
      qf[m][kk] = *(const bf16x8*)(qkv + row * 3072 + h * 64 + kk * 32 + g * 8);
    }
  bf16x8 ones;
#pragma unroll
  for (int j = 0; j < 8; ++j) ones[j] = (bf16)1.0f;

  f32x4 oacc[2][4] = {};
  f32x4 lacc[2] = {};
  float mrun[2][4];
#pragma unroll
  for (int m = 0; m < 2; ++m)
#pragma unroll
    for (int i = 0; i < 4; ++i) mrun[m][i] = -3.0e38f;

  const int nkt = 2 * qt + 2;
  const int qlow = qt * 128 + wave * 32;  // lowest q row of this wave

#define STAGE(KT, BUF)                                                                     \
  do {                                                                                     \
    _Pragma("unroll") for (int t = 0; t < 2; ++t) {                                        \
      int o = t * 4096 + wave * 1024 + lane * 16;                                          \
      int r = o >> 7, chs = ((o & 127) >> 4) ^ (r & 7);                                    \
      gload16((const char*)qkv +                                                           \
                  ((size_t)(b * 2048 + (KT)*64 + r) * 3072 + 1024 + h * 64) * 2 +          \
                  (chs << 4),                                                              \
              (char*)Ks[BUF] + o);                                                         \
      gload16((const char*)vt + (((size_t)bh * 64 + r) * 2048 + (KT)*64) * 2 + (chs << 4), \
              (char*)Vs[BUF] + o);                                                         \
    }                                                                                      \
  } while (0)

  STAGE(0, 0);  // prologue
  for (int kt = 0; kt < nkt; ++kt) {
    const int cur = kt & 1;
    if (kt + 1 < nkt) {
      STAGE(kt + 1, cur ^ 1);
      asm volatile("s_waitcnt vmcnt(4)" ::: "memory");  // current tile landed
    } else {
      asm volatile("s_waitcnt vmcnt(0)" ::: "memory");
    }
    __builtin_amdgcn_sched_barrier(0);
    __builtin_amdgcn_s_barrier();
    __builtin_amdgcn_sched_barrier(0);
    if (kt * 64 <= qlow + 31) {  // wave-uniform: skip fully-masked tiles
      f32x4 sc[2][4] = {};
      __builtin_amdgcn_s_setprio(1);
#pragma unroll
      for (int n = 0; n < 4; ++n) {
        int key = n * 16 + c;
#pragma unroll
        for (int kk = 0; kk < 2; ++kk) {
          bf16x8 kf = *(const bf16x8*)((const char*)Ks[cur] + key * 128 +
                                       (((kk * 4 + g) ^ (key & 7)) << 4));
#pragma unroll
          for (int m = 0; m < 2; ++m) sc[m][n] = mfma16(qf[m][kk], kf, sc[m][n]);
        }
      }
      __builtin_amdgcn_s_setprio(0);
      // online softmax in exp2 domain; mask only on diagonal tiles
      const bool domask = (kt * 64 + 63) > qlow;
#pragma unroll
      for (int m = 0; m < 2; ++m)
#pragma unroll
        for (int i = 0; i < 4; ++i) {
          const int q = qlow + m * 16 + 4 * g + i;
          float vmax = -3.0e38f;
#pragma unroll
          for (int n = 0; n < 4; ++n) {
            float s = sc[m][n][i];
            if (domask) s = ((kt * 64 + n * 16 + c) <= q) ? s : -3.0e38f;
            sc[m][n][i] = s;
            vmax = fmaxf(vmax, s);
          }
          vmax = fmaxf(vmax, __shfl_xor(vmax, 1));
          vmax = fmaxf(vmax, __shfl_xor(vmax, 2));
          vmax = fmaxf(vmax, __shfl_xor(vmax, 4));
          vmax = fmaxf(vmax, __shfl_xor(vmax, 8));
          const float mnew = fmaxf(mrun[m][i], vmax * SCL);
          const float fs = __builtin_amdgcn_exp2f(mrun[m][i] - mnew);
          mrun[m][i] = mnew;
#pragma unroll
          for (int n = 0; n < 4; ++n) {
            float p = __builtin_amdgcn_exp2f(fmaf(sc[m][n][i], SCL, -mnew));
            Ps[wave][(m * 16 + 4 * g + i) * 72 + n * 16 + c] = (bf16)p;
          }
          lacc[m][i] *= fs;
#pragma unroll
          for (int dn = 0; dn < 4; ++dn) oacc[m][dn][i] *= fs;
        }
      asm volatile("s_waitcnt lgkmcnt(0)" ::: "memory");
      __builtin_amdgcn_sched_barrier(0);
      // PV + row-sum (l) via MFMA against ones
      __builtin_amdgcn_s_setprio(1);
#pragma unroll
      for (int kk = 0; kk < 2; ++kk) {
        bf16x8 vf[4];
#pragma unroll
        for (int dn = 0; dn < 4; ++dn) {
          int d = dn * 16 + c;
          vf[dn] = *(const bf16x8*)((const char*)Vs[cur] + d * 128 +
                                    (((kk * 4 + g) ^ (d & 7)) << 4));
        }
#pragma unroll
        for (int m = 0; m < 2; ++m) {
          bf16x8 pf = *(const bf16x8*)((const char*)Ps[wave] + (m * 16 + c) * 144 +
                                       kk * 64 + g * 16);
          lacc[m] = mfma16(pf, ones, lacc[m]);
#pragma unroll
          for (int dn = 0; dn < 4; ++dn) oacc[m][dn] = mfma16(pf, vf[dn], oacc[m][dn]);
        }
      }
      __builtin_amdgcn_s_setprio(0);
    }
    __builtin_amdgcn_sched_barrier(0);
    __builtin_amdgcn_s_barrier();  // readers done before next-tile overwrite
    __builtin_amdgcn_sched_barrier(0);
  }
#undef STAGE
  // epilogue: normalize, store bf16 [8192][1024]
#pragma unroll
  for (int m = 0; m < 2; ++m)
#pragma unroll
    for (int i = 0; i < 4; ++i) {
      float inv = __builtin_amdgcn_rcpf(lacc[m][i]);
      size_t row = (size_t)(b * 2048 + qt * 128 + wave * 32 + m * 16 + 4 * g + i);
#pragma unroll
      for (int dn = 0; dn < 4; ++dn)
        attn_out[row * 1024 + h * 64 + dn * 16 + c] = (bf16)(oacc[m][dn][i] * inv);
    }
}

// ---------------- launch ----------------
extern "C" void kernel_launch(void* const* d_in, const int* in_sizes, int n_in,
                              void* d_out, int out_size, void* d_ws, size_t ws_size,
                              hipStream_t stream) {
  const float* x  = (const float*)d_in[0];
  const float* Wq = (const float*)d_in[1];
  const float* Wk = (const float*)d_in[2];
  const float* Wv = (const float*)d_in[3];
  const float* Wo = (const float*)d_in[4];
  const float* bo = (const float*)d_in[5];
  float* out = (float*)d_out;
  char* ws = (char*)d_ws;

  bf16* Xb    = (bf16*)(ws);
  bf16* WqkvT = (bf16*)(ws + 16777216);
  bf16* WoT   = (bf16*)(ws + 23068672);
  bf16* QKV   = (bf16*)(ws + 25165824);
  bf16* VT    = (bf16*)(ws + 75497472);
  bf16* AttnO = (bf16*)(ws + 92274688);

  pack_x_kernel<<<8192, 256, 0, stream>>>(x, Xb);
  pack_wqkv_kernel<<<12288, 256, 0, stream>>>(Wq, Wk, Wv, WqkvT);
  pack_wo_kernel<<<4096, 256, 0, stream>>>(Wo, WoT);
  gemm_bt_kernel<false><<<dim3(24, 64), 256, 0, stream>>>(Xb, WqkvT, QKV, nullptr, nullptr,
                                                          8192, 3072, 1024);
  transpose_v_kernel<<<dim3(32, 64), 256, 0, stream>>>(QKV, VT);
  attn_kernel<<<1024, 256, 0, stream>>>(QKV, VT, AttnO);
  gemm_bt_kernel<true><<<dim3(8, 64), 256, 0, stream>>>(AttnO, WoT, nullptr, out, bo,
                                                        8192, 1024, 1024);
}

// Round 5
// 234.442 us; speedup vs baseline: 1.5121x; 1.2190x over previous
//
#include <hip/hip_runtime.h>

// B=4, S=2048, D=1024, H=16, HS=64. Full bf16-MFMA pipeline.
// Workspace layout (needs ~104 MiB):
//   Xb     @ 0         : x as bf16            [8192][1024]   16 MiB
//   WqkvT  @ 16777216  : qkv weights B^T bf16 [3072][1024]    6 MiB
//   WoT    @ 23068672  : Wo^T bf16            [1024][1024]    2 MiB
//   QKV    @ 25165824  : Q|K|V bf16           [8192][3072]   48 MiB
//   VT     @ 75497472  : V^T bf16             [64bh][64][2048] 16 MiB
//   AttnO  @ 92274688  : attention out bf16   [8192][1024]   16 MiB

typedef __bf16 bf16;
typedef bf16 bf16x8 __attribute__((ext_vector_type(8)));
typedef bf16 bf16x4 __attribute__((ext_vector_type(4)));
typedef float f32x4 __attribute__((ext_vector_type(4)));

__device__ __forceinline__ void gload16(const void* gsrc, void* ldst) {
  __builtin_amdgcn_global_load_lds(
      (const __attribute__((address_space(1))) unsigned int*)gsrc,
      (__attribute__((address_space(3))) unsigned int*)ldst, 16, 0, 0);
}

__device__ __forceinline__ f32x4 mfma16(bf16x8 a, bf16x8 b, f32x4 c) {
  return __builtin_amdgcn_mfma_f32_16x16x32_bf16(a, b, c, 0, 0, 0);
}

// ---------------- pack kernels ----------------
__global__ __launch_bounds__(256) void pack_x_kernel(const float* __restrict__ x,
                                                     bf16* __restrict__ xb) {
  int i = (blockIdx.x * 256 + threadIdx.x) * 4;  // grid sized exactly
  float4 v = *(const float4*)(x + i);
  bf16x4 o;
  o[0] = (bf16)v.x; o[1] = (bf16)v.y; o[2] = (bf16)v.z; o[3] = (bf16)v.w;
  *(bf16x4*)(xb + i) = o;
}

// WT[n][k] = W{q,k,v}[h = (n%1024)/64][k][e = n%64], n in [0,3072)
__global__ __launch_bounds__(256) void pack_wqkv_kernel(const float* __restrict__ Wq,
                                                        const float* __restrict__ Wk,
                                                        const float* __restrict__ Wv,
                                                        bf16* __restrict__ WT) {
  int idx = blockIdx.x * 256 + threadIdx.x;  // 0..3145727
  int n = idx >> 10, k = idx & 1023;
  int sel = n >> 10, nn = n & 1023;
  const float* W = (sel == 0) ? Wq : (sel == 1 ? Wk : Wv);
  int h = nn >> 6, e = nn & 63;
  WT[(size_t)n * 1024 + k] = (bf16)W[h * 65536 + k * 64 + e];
}

// WoT[n][k] = Wo[k][n]
__global__ __launch_bounds__(256) void pack_wo_kernel(const float* __restrict__ Wo,
                                                      bf16* __restrict__ WoT) {
  int idx = blockIdx.x * 256 + threadIdx.x;  // 0..1048575
  int n = idx >> 10, k = idx & 1023;
  WoT[idx] = (bf16)Wo[k * 1024 + n];
}

// ---------------- GEMM: C[M][N] = A[M][K] * BT[N][K]^T ----------------
// 128x128 tile, BK=32, 4 waves (2x2), each wave 64x64 (4x4 frags of 16x16x32).
template <bool F32OUT>
__global__ __launch_bounds__(256) void gemm_bt_kernel(const bf16* __restrict__ A,
                                                      const bf16* __restrict__ BT,
                                                      bf16* __restrict__ Cb,
                                                      float* __restrict__ Cf,
                                                      const float* __restrict__ bias,
                                                      int M, int N, int K) {
  __shared__ bf16 As[128 * 32];
  __shared__ bf16 Bs[128 * 32];
  const int tid = threadIdx.x, lane = tid & 63, wave = tid >> 6;
  const int g = lane >> 4, c = lane & 15;
  // bijective XCD swizzle (grid sizes are multiples of 8)
  const int nx = gridDim.x;
  const int nwg = nx * gridDim.y;
  const int bid = blockIdx.y * nx + blockIdx.x;
  const int swz = (bid & 7) * (nwg >> 3) + (bid >> 3);
  const int m0 = (swz / nx) * 128, n0 = (swz % nx) * 128;
  const int wr = wave >> 1, wc = wave & 1;

  f32x4 acc[4][4] = {};
  for (int k0 = 0; k0 < K; k0 += 32) {
#pragma unroll
    for (int t = 0; t < 2; ++t) {
      int o = t * 4096 + wave * 1024 + lane * 16;  // byte offset in 8KB tile
      int row = o >> 6, kb = (o & 63) >> 1;        // row, k-elem within BK
      gload16(A + (size_t)(m0 + row) * K + k0 + kb, (char*)As + o);
      gload16(BT + (size_t)(n0 + row) * K + k0 + kb, (char*)Bs + o);
    }
    __syncthreads();
    bf16x8 af[4], bfr[4];
#pragma unroll
    for (int m = 0; m < 4; ++m)
      af[m] = *(const bf16x8*)((const char*)As + (wr * 64 + m * 16 + c) * 64 + g * 16);
#pragma unroll
    for (int n = 0; n < 4; ++n)
      bfr[n] = *(const bf16x8*)((const char*)Bs + (wc * 64 + n * 16 + c) * 64 + g * 16);
#pragma unroll
    for (int m = 0; m < 4; ++m)
#pragma unroll
      for (int n = 0; n < 4; ++n)
        acc[m][n] = mfma16(af[m], bfr[n], acc[m][n]);
    __syncthreads();
  }
#pragma unroll
  for (int m = 0; m < 4; ++m)
#pragma unroll
    for (int n = 0; n < 4; ++n)
#pragma unroll
      for (int i = 0; i < 4; ++i) {
        int row = m0 + wr * 64 + m * 16 + g * 4 + i;
        int col = n0 + wc * 64 + n * 16 + c;
        if (F32OUT)
          Cf[(size_t)row * N + col] = acc[m][n][i] + bias[col];
        else
          Cb[(size_t)row * N + col] = (bf16)acc[m][n][i];
      }
}

// ---------------- V transpose: VT[bh][d][s] = V[b,s,h,d] ----------------
// 64x64 tile per block; 512 bf16x8 chunks per side -> 2 iterations per thread.
__global__ __launch_bounds__(256) void transpose_v_kernel(const bf16* __restrict__ qkv,
                                                          bf16* __restrict__ vt) {
  __shared__ bf16 tl[64][72];  // stride 144B keeps 16B alignment for b128 stores
  const int tid = threadIdx.x;
  const int st = blockIdx.x, bh = blockIdx.y;
  const int b = bh >> 4, h = bh & 15;
#pragma unroll
  for (int it = 0; it < 2; ++it) {
    int idx = it * 256 + tid;          // 0..511
    int sl = idx >> 3, ch = idx & 7;   // sl 0..63 (s row), ch 0..7 (d chunk)
    bf16x8 v = *(const bf16x8*)(qkv + (size_t)(b * 2048 + st * 64 + sl) * 3072 + 2048 + h * 64 + ch * 8);
    *(bf16x8*)&tl[sl][ch * 8] = v;
  }
  __syncthreads();
#pragma unroll
  for (int it = 0; it < 2; ++it) {
    int idx = it * 256 + tid;
    int d = idx >> 3, s8 = idx & 7;    // d 0..63, s chunk 0..7
    bf16x8 o;
#pragma unroll
    for (int j = 0; j < 8; ++j) o[j] = tl[s8 * 8 + j][d];
    *(bf16x8*)(vt + ((size_t)bh * 64 + d) * 2048 + st * 64 + s8 * 8) = o;
  }
}

// ---------------- causal flash attention ----------------
// 1D grid of 1024 blocks, balanced qt mapping. 256 threads = 4 waves,
// 32 q-rows/wave, K-tiles of 64, double-buffered staging (counted vmcnt).
// Swapped QK^T (mfma(K,Q)): S lane layout q=c, key=4g+i -> softmax is
// per-lane in q and the PV A-fragment (k = g*8+j with kappa(k) =
// kss*32 + (j<4 ? 4g+j : 16+4g+j-4)) is entirely in-lane: no P LDS
// round-trip. LDS = 32KB -> 4 blocks/CU (VGPR-capped via launch_bounds).
__global__ __launch_bounds__(256, 4) void attn_kernel(const bf16* __restrict__ qkv,
                                                      const bf16* __restrict__ vt,
                                                      bf16* __restrict__ attn_out) {
  __shared__ bf16 Ks[2][64 * 64];    // [key][hd], chunk-swizzled
  __shared__ bf16 Vs[2][64 * 64];    // [d][key], chunk-swizzled
  const int tid = threadIdx.x, lane = tid & 63, wave = tid >> 6;
  const int g = lane >> 4, c = lane & 15;
  const int bid = blockIdx.x;
  const int x = bid & 15;
  const int bh = bid >> 4;
  const int qt = ((bh >> 4) & 1) ? (15 - x) : x;
  const int b = bh >> 4, h = bh & 15;
  const float SCL = 0.125f * 1.4426950408889634f;  // log2(e) * scale

  bf16x8 qf[2][2];
#pragma unroll
  for (int m = 0; m < 2; ++m)
#pragma unroll
    for (int kk = 0; kk < 2; ++kk) {
      size_t row = (size_t)(b * 2048 + qt * 128 + wave * 32 + m * 16 + c);
      qf[m][kk] = *(const bf16x8*)(qkv + row * 3072 + h * 64 + kk * 32 + g * 8);
    }

  f32x4 oacc[2][4] = {};
  float mrun[2] = {-3.0e38f, -3.0e38f};  // per-lane: q = m*16+c
  float lrun[2] = {0.f, 0.f};

  const int nkt = 2 * qt + 2;
  const int qlow = qt * 128 + wave * 32;  // lowest q row of this wave

#define STAGE(KT, BUF)                                                                     \
  do {                                                                                     \
    _Pragma("unroll") for (int t = 0; t < 2; ++t) {                                        \
      int o = t * 4096 + wave * 1024 + lane * 16;                                          \
      int r = o >> 7, chs = ((o & 127) >> 4) ^ (r & 7);                                    \
      gload16((const char*)qkv +                                                           \
                  ((size_t)(b * 2048 + (KT)*64 + r) * 3072 + 1024 + h * 64) * 2 +          \
                  (chs << 4),                                                              \
              (char*)Ks[BUF] + o);                                                         \
      gload16((const char*)vt + (((size_t)bh * 64 + r) * 2048 + (KT)*64) * 2 + (chs << 4), \
              (char*)Vs[BUF] + o);                                                         \
    }                                                                                      \
  } while (0)

  STAGE(0, 0);  // prologue
  for (int kt = 0; kt < nkt; ++kt) {
    const int cur = kt & 1;
    if (kt + 1 < nkt) {
      STAGE(kt + 1, cur ^ 1);
      asm volatile("s_waitcnt vmcnt(4)" ::: "memory");  // current tile landed
    } else {
      asm volatile("s_waitcnt vmcnt(0)" ::: "memory");
    }
    __builtin_amdgcn_sched_barrier(0);
    __builtin_amdgcn_s_barrier();
    __builtin_amdgcn_sched_barrier(0);
    if (kt * 64 <= qlow + 31) {  // wave-uniform: skip fully-masked tiles
      // QK^T swapped: sc[n][m] holds S[key = kt*64+n*16+4g+i][q = m*16+c]
      f32x4 sc[4][2] = {};
      __builtin_amdgcn_s_setprio(1);
#pragma unroll
      for (int n = 0; n < 4; ++n) {
        int key = n * 16 + c;
#pragma unroll
        for (int kk = 0; kk < 2; ++kk) {
          bf16x8 kf = *(const bf16x8*)((const char*)Ks[cur] + key * 128 +
                                       (((kk * 4 + g) ^ (key & 7)) << 4));
#pragma unroll
          for (int m = 0; m < 2; ++m) sc[n][m] = mfma16(kf, qf[m][kk], sc[n][m]);
        }
      }
      __builtin_amdgcn_s_setprio(0);
      const bool domask = (kt * 64 + 63) > qlow;
      bf16x8 pa[2][2];  // PV A-frags [m][kss], built fully in-lane
#pragma unroll
      for (int m = 0; m < 2; ++m) {
        const int q = qlow + m * 16 + c;
        float vmax = -3.0e38f;
#pragma unroll
        for (int n = 0; n < 4; ++n)
#pragma unroll
          for (int i = 0; i < 4; ++i) {
            float s = sc[n][m][i];
            if (domask) s = ((kt * 64 + n * 16 + 4 * g + i) <= q) ? s : -3.0e38f;
            sc[n][m][i] = s;
            vmax = fmaxf(vmax, s);
          }
        vmax = fmaxf(vmax, __shfl_xor(vmax, 16));
        vmax = fmaxf(vmax, __shfl_xor(vmax, 32));
        const float mnew = fmaxf(mrun[m], vmax * SCL);
        const float fs = __builtin_amdgcn_exp2f(mrun[m] - mnew);
        mrun[m] = mnew;
        float lsum = 0.f;
#pragma unroll
        for (int n = 0; n < 4; ++n)
#pragma unroll
          for (int i = 0; i < 4; ++i) {
            float p = __builtin_amdgcn_exp2f(fmaf(sc[n][m][i], SCL, -mnew));
            sc[n][m][i] = p;
            lsum += p;
          }
        lsum += __shfl_xor(lsum, 16);
        lsum += __shfl_xor(lsum, 32);
        lrun[m] = lrun[m] * fs + lsum;
        // broadcast fs from softmax layout (q=c) to oacc layout (q=4g+i)
#pragma unroll
        for (int i = 0; i < 4; ++i) {
          float fsb = __shfl(fs, ((lane >> 4) << 2) + i);
#pragma unroll
          for (int dn = 0; dn < 4; ++dn) oacc[m][dn][i] *= fsb;
        }
        // pack PV A-frags: kappa = kss*32 + (j<4 ? 4g+j : 16+4g+(j-4))
#pragma unroll
        for (int kss = 0; kss < 2; ++kss) {
          bf16x8 t;
#pragma unroll
          for (int j = 0; j < 4; ++j) t[j] = (bf16)sc[2 * kss][m][j];
#pragma unroll
          for (int j = 0; j < 4; ++j) t[4 + j] = (bf16)sc[2 * kss + 1][m][j];
          pa[m][kss] = t;
        }
      }
      // PV: vb B-frag k = g*8+j with same kappa mapping; two b64 reads each
      __builtin_amdgcn_s_setprio(1);
#pragma unroll
      for (int kss = 0; kss < 2; ++kss) {
#pragma unroll
        for (int dn = 0; dn < 4; ++dn) {
          const int d = dn * 16 + c;
          const char* vrow = (const char*)Vs[cur] + d * 128;
          const int off = 8 * (g & 1);
          bf16x4 lo = *(const bf16x4*)(vrow + (((4 * kss + (g >> 1)) ^ (d & 7)) << 4) + off);
          bf16x4 hi = *(const bf16x4*)(vrow + (((4 * kss + 2 + (g >> 1)) ^ (d & 7)) << 4) + off);
          bf16x8 vb;
#pragma unroll
          for (int j = 0; j < 4; ++j) { vb[j] = lo[j]; vb[4 + j] = hi[j]; }
#pragma unroll
          for (int m = 0; m < 2; ++m) oacc[m][dn] = mfma16(pa[m][kss], vb, oacc[m][dn]);
        }
      }
      __builtin_amdgcn_s_setprio(0);
    }
    __builtin_amdgcn_sched_barrier(0);
    __builtin_amdgcn_s_barrier();  // readers done before next-tile overwrite
    __builtin_amdgcn_sched_barrier(0);
  }
#undef STAGE
  // epilogue: normalize, store bf16 [8192][1024]
#pragma unroll
  for (int m = 0; m < 2; ++m) {
    float inv = __builtin_amdgcn_rcpf(lrun[m]);  // lane q = m*16+c
#pragma unroll
    for (int i = 0; i < 4; ++i) {
      float invb = __shfl(inv, ((lane >> 4) << 2) + i);
      size_t row = (size_t)(b * 2048 + qt * 128 + wave * 32 + m * 16 + 4 * g + i);
#pragma unroll
      for (int dn = 0; dn < 4; ++dn)
        attn_out[row * 1024 + h * 64 + dn * 16 + c] = (bf16)(oacc[m][dn][i] * invb);
    }
  }
}

// ---------------- launch ----------------
extern "C" void kernel_launch(void* const* d_in, const int* in_sizes, int n_in,
                              void* d_out, int out_size, void* d_ws, size_t ws_size,
                              hipStream_t stream) {
  const float* x  = (const float*)d_in[0];
  const float* Wq = (const float*)d_in[1];
  const float* Wk = (const float*)d_in[2];
  const float* Wv = (const float*)d_in[3];
  const float* Wo = (const float*)d_in[4];
  const float* bo = (const float*)d_in[5];
  float* out = (float*)d_out;
  char* ws = (char*)d_ws;

  bf16* Xb    = (bf16*)(ws);
  bf16* WqkvT = (bf16*)(ws + 16777216);
  bf16* WoT   = (bf16*)(ws + 23068672);
  bf16* QKV   = (bf16*)(ws + 25165824);
  bf16* VT    = (bf16*)(ws + 75497472);
  bf16* AttnO = (bf16*)(ws + 92274688);

  pack_x_kernel<<<8192, 256, 0, stream>>>(x, Xb);
  pack_wqkv_kernel<<<12288, 256, 0, stream>>>(Wq, Wk, Wv, WqkvT);
  pack_wo_kernel<<<4096, 256, 0, stream>>>(Wo, WoT);
  gemm_bt_kernel<false><<<dim3(24, 64), 256, 0, stream>>>(Xb, WqkvT, QKV, nullptr, nullptr,
                                                          8192, 3072, 1024);
  transpose_v_kernel<<<dim3(32, 64), 256, 0, stream>>>(QKV, VT);
  attn_kernel<<<1024, 256, 0, stream>>>(QKV, VT, AttnO);
  gemm_bt_kernel<true><<<dim3(8, 64), 256, 0, stream>>>(AttnO, WoT, nullptr, out, bo,
                                                        8192, 1024, 1024);
}

// Round 6
// 216.899 us; speedup vs baseline: 1.6344x; 1.0809x over previous
//
#include <hip/hip_runtime.h>

// B=4, S=2048, D=1024, H=16, HS=64. Full bf16-MFMA pipeline.
// Workspace layout (needs ~104 MiB):
//   Xb     @ 0         : x as bf16            [8192][1024]   16 MiB
//   WqkvT  @ 16777216  : qkv weights B^T bf16 [3072][1024]    6 MiB
//   WoT    @ 23068672  : Wo^T bf16            [1024][1024]    2 MiB
//   QKV    @ 25165824  : Q|K|V bf16           [8192][3072]   48 MiB
//   VT     @ 75497472  : V^T bf16             [64bh][64][2048] 16 MiB
//   AttnO  @ 92274688  : attention out bf16   [8192][1024]   16 MiB

typedef __bf16 bf16;
typedef bf16 bf16x8 __attribute__((ext_vector_type(8)));
typedef bf16 bf16x4 __attribute__((ext_vector_type(4)));
typedef float f32x4 __attribute__((ext_vector_type(4)));

__device__ __forceinline__ void gload16(const void* gsrc, void* ldst) {
  __builtin_amdgcn_global_load_lds(
      (const __attribute__((address_space(1))) unsigned int*)gsrc,
      (__attribute__((address_space(3))) unsigned int*)ldst, 16, 0, 0);
}

__device__ __forceinline__ f32x4 mfma16(bf16x8 a, bf16x8 b, f32x4 c) {
  return __builtin_amdgcn_mfma_f32_16x16x32_bf16(a, b, c, 0, 0, 0);
}

// ---------------- pack kernels ----------------
__global__ __launch_bounds__(256) void pack_x_kernel(const float* __restrict__ x,
                                                     bf16* __restrict__ xb) {
  int i = (blockIdx.x * 256 + threadIdx.x) * 4;  // grid sized exactly
  float4 v = *(const float4*)(x + i);
  bf16x4 o;
  o[0] = (bf16)v.x; o[1] = (bf16)v.y; o[2] = (bf16)v.z; o[3] = (bf16)v.w;
  *(bf16x4*)(xb + i) = o;
}

// WT[n][k] = W{q,k,v}[h = (n%1024)/64][k][e = n%64], n in [0,3072)
__global__ __launch_bounds__(256) void pack_wqkv_kernel(const float* __restrict__ Wq,
                                                        const float* __restrict__ Wk,
                                                        const float* __restrict__ Wv,
                                                        bf16* __restrict__ WT) {
  int idx = blockIdx.x * 256 + threadIdx.x;  // 0..3145727
  int n = idx >> 10, k = idx & 1023;
  int sel = n >> 10, nn = n & 1023;
  const float* W = (sel == 0) ? Wq : (sel == 1 ? Wk : Wv);
  int h = nn >> 6, e = nn & 63;
  WT[(size_t)n * 1024 + k] = (bf16)W[h * 65536 + k * 64 + e];
}

// WoT[n][k] = Wo[k][n]
__global__ __launch_bounds__(256) void pack_wo_kernel(const float* __restrict__ Wo,
                                                      bf16* __restrict__ WoT) {
  int idx = blockIdx.x * 256 + threadIdx.x;  // 0..1048575
  int n = idx >> 10, k = idx & 1023;
  WoT[idx] = (bf16)Wo[k * 1024 + n];
}

// ---------------- GEMM: C[M][N] = A[M][K] * BT[N][K]^T ----------------
// 128x128 tile, BK=32, 4 waves (2x2), each wave 64x64 (4x4 frags of 16x16x32).
template <bool F32OUT>
__global__ __launch_bounds__(256) void gemm_bt_kernel(const bf16* __restrict__ A,
                                                      const bf16* __restrict__ BT,
                                                      bf16* __restrict__ Cb,
                                                      float* __restrict__ Cf,
                                                      const float* __restrict__ bias,
                                                      int M, int N, int K) {
  __shared__ bf16 As[128 * 32];
  __shared__ bf16 Bs[128 * 32];
  const int tid = threadIdx.x, lane = tid & 63, wave = tid >> 6;
  const int g = lane >> 4, c = lane & 15;
  // bijective XCD swizzle (grid sizes are multiples of 8)
  const int nx = gridDim.x;
  const int nwg = nx * gridDim.y;
  const int bid = blockIdx.y * nx + blockIdx.x;
  const int swz = (bid & 7) * (nwg >> 3) + (bid >> 3);
  const int m0 = (swz / nx) * 128, n0 = (swz % nx) * 128;
  const int wr = wave >> 1, wc = wave & 1;

  f32x4 acc[4][4] = {};
  for (int k0 = 0; k0 < K; k0 += 32) {
#pragma unroll
    for (int t = 0; t < 2; ++t) {
      int o = t * 4096 + wave * 1024 + lane * 16;  // byte offset in 8KB tile
      int row = o >> 6, kb = (o & 63) >> 1;        // row, k-elem within BK
      gload16(A + (size_t)(m0 + row) * K + k0 + kb, (char*)As + o);
      gload16(BT + (size_t)(n0 + row) * K + k0 + kb, (char*)Bs + o);
    }
    __syncthreads();
    bf16x8 af[4], bfr[4];
#pragma unroll
    for (int m = 0; m < 4; ++m)
      af[m] = *(const bf16x8*)((const char*)As + (wr * 64 + m * 16 + c) * 64 + g * 16);
#pragma unroll
    for (int n = 0; n < 4; ++n)
      bfr[n] = *(const bf16x8*)((const char*)Bs + (wc * 64 + n * 16 + c) * 64 + g * 16);
#pragma unroll
    for (int m = 0; m < 4; ++m)
#pragma unroll
      for (int n = 0; n < 4; ++n)
        acc[m][n] = mfma16(af[m], bfr[n], acc[m][n]);
    __syncthreads();
  }
#pragma unroll
  for (int m = 0; m < 4; ++m)
#pragma unroll
    for (int n = 0; n < 4; ++n)
#pragma unroll
      for (int i = 0; i < 4; ++i) {
        int row = m0 + wr * 64 + m * 16 + g * 4 + i;
        int col = n0 + wc * 64 + n * 16 + c;
        if (F32OUT)
          Cf[(size_t)row * N + col] = acc[m][n][i] + bias[col];
        else
          Cb[(size_t)row * N + col] = (bf16)acc[m][n][i];
      }
}

// ---------------- V transpose: VT[bh][d][s] = V[b,s,h,d] ----------------
// 64x64 tile per block; 512 bf16x8 chunks per side -> 2 iterations per thread.
__global__ __launch_bounds__(256) void transpose_v_kernel(const bf16* __restrict__ qkv,
                                                          bf16* __restrict__ vt) {
  __shared__ bf16 tl[64][72];  // stride 144B keeps 16B alignment for b128 stores
  const int tid = threadIdx.x;
  const int st = blockIdx.x, bh = blockIdx.y;
  const int b = bh >> 4, h = bh & 15;
#pragma unroll
  for (int it = 0; it < 2; ++it) {
    int idx = it * 256 + tid;          // 0..511
    int sl = idx >> 3, ch = idx & 7;   // sl 0..63 (s row), ch 0..7 (d chunk)
    bf16x8 v = *(const bf16x8*)(qkv + (size_t)(b * 2048 + st * 64 + sl) * 3072 + 2048 + h * 64 + ch * 8);
    *(bf16x8*)&tl[sl][ch * 8] = v;
  }
  __syncthreads();
#pragma unroll
  for (int it = 0; it < 2; ++it) {
    int idx = it * 256 + tid;
    int d = idx >> 3, s8 = idx & 7;    // d 0..63, s chunk 0..7
    bf16x8 o;
#pragma unroll
    for (int j = 0; j < 8; ++j) o[j] = tl[s8 * 8 + j][d];
    *(bf16x8*)(vt + ((size_t)bh * 64 + d) * 2048 + st * 64 + s8 * 8) = o;
  }
}

// ---------------- causal flash attention ----------------
// Grid = 512 blocks x 512 threads (8 waves, 16 q-rows/wave). Block (x,bh),
// x = bid&7, bh = bid>>3, processes qt=x then qt=15-x sequentially: every
// block runs exactly (2x+2)+(32-2x) = 34 K-tiles -> uniform makespan, 2
// blocks/CU x 8 waves = 16 waves/CU sustained (no short-block drain tail).
// Swapped QK^T (mfma(K,Q)): per-lane softmax (q=c), in-lane PV A-frags.
// Double-buffered K/V staging, counted vmcnt (STAGE = 2 loads/thread).
__global__ __launch_bounds__(512, 4) void attn_kernel(const bf16* __restrict__ qkv,
                                                      const bf16* __restrict__ vt,
                                                      bf16* __restrict__ attn_out) {
  __shared__ bf16 Ks[2][64 * 64];    // [key][hd], chunk-swizzled
  __shared__ bf16 Vs[2][64 * 64];    // [d][key], chunk-swizzled
  const int tid = threadIdx.x, lane = tid & 63, wave = tid >> 6;
  const int g = lane >> 4, c = lane & 15;
  const int bid = blockIdx.x;
  const int x = bid & 7;
  const int bh = bid >> 3;
  const int b = bh >> 4, h = bh & 15;
  const float SCL = 0.125f * 1.4426950408889634f;  // log2(e) * scale

#define STAGE(KT, BUF)                                                                     \
  do {                                                                                     \
    int o = wave * 1024 + lane * 16;                                                       \
    int r = o >> 7, chs = ((o & 127) >> 4) ^ (r & 7);                                      \
    gload16((const char*)qkv +                                                             \
                ((size_t)(b * 2048 + (KT)*64 + r) * 3072 + 1024 + h * 64) * 2 +            \
                (chs << 4),                                                                \
            (char*)Ks[BUF] + o);                                                           \
    gload16((const char*)vt + (((size_t)bh * 64 + r) * 2048 + (KT)*64) * 2 + (chs << 4),   \
            (char*)Vs[BUF] + o);                                                           \
  } while (0)

#pragma unroll 1
  for (int ph = 0; ph < 2; ++ph) {
    const int qt = ph ? (15 - x) : x;
    const int qlow = qt * 128 + wave * 16;  // lowest q row of this wave

    bf16x8 qf[2];
#pragma unroll
    for (int kk = 0; kk < 2; ++kk) {
      size_t row = (size_t)(b * 2048 + qlow + c);
      qf[kk] = *(const bf16x8*)(qkv + row * 3072 + h * 64 + kk * 32 + g * 8);
    }

    f32x4 oacc[4] = {};
    float mrun = -3.0e38f;  // per-lane: q = qlow + c
    float lrun = 0.f;

    const int nkt = 2 * qt + 2;
    STAGE(0, 0);  // prologue
    for (int kt = 0; kt < nkt; ++kt) {
      const int cur = kt & 1;
      if (kt + 1 < nkt) {
        STAGE(kt + 1, cur ^ 1);
        asm volatile("s_waitcnt vmcnt(2)" ::: "memory");  // current tile landed
      } else {
        asm volatile("s_waitcnt vmcnt(0)" ::: "memory");
      }
      __builtin_amdgcn_sched_barrier(0);
      __builtin_amdgcn_s_barrier();
      __builtin_amdgcn_sched_barrier(0);
      if (kt * 64 <= qlow + 15) {  // wave-uniform: skip fully-masked tiles
        // QK^T swapped: sc[n] holds S[key = kt*64+n*16+4g+i][q = qlow+c]
        f32x4 sc[4] = {};
        __builtin_amdgcn_s_setprio(1);
#pragma unroll
        for (int n = 0; n < 4; ++n) {
          int key = n * 16 + c;
#pragma unroll
          for (int kk = 0; kk < 2; ++kk) {
            bf16x8 kf = *(const bf16x8*)((const char*)Ks[cur] + key * 128 +
                                         (((kk * 4 + g) ^ (key & 7)) << 4));
            sc[n] = mfma16(kf, qf[kk], sc[n]);
          }
        }
        __builtin_amdgcn_s_setprio(0);
        const bool domask = (kt * 64 + 63) > qlow;
        const int q = qlow + c;
        float vmax = -3.0e38f;
#pragma unroll
        for (int n = 0; n < 4; ++n)
#pragma unroll
          for (int i = 0; i < 4; ++i) {
            float s = sc[n][i];
            if (domask) s = ((kt * 64 + n * 16 + 4 * g + i) <= q) ? s : -3.0e38f;
            sc[n][i] = s;
            vmax = fmaxf(vmax, s);
          }
        vmax = fmaxf(vmax, __shfl_xor(vmax, 16));
        vmax = fmaxf(vmax, __shfl_xor(vmax, 32));
        const float mnew = fmaxf(mrun, vmax * SCL);
        const float fs = __builtin_amdgcn_exp2f(mrun - mnew);
        mrun = mnew;
        float lsum = 0.f;
#pragma unroll
        for (int n = 0; n < 4; ++n)
#pragma unroll
          for (int i = 0; i < 4; ++i) {
            float p = __builtin_amdgcn_exp2f(fmaf(sc[n][i], SCL, -mnew));
            sc[n][i] = p;
            lsum += p;
          }
        lsum += __shfl_xor(lsum, 16);
        lsum += __shfl_xor(lsum, 32);
        lrun = lrun * fs + lsum;
        // broadcast fs from softmax layout (q=c) to oacc layout (q=4g+i)
#pragma unroll
        for (int i = 0; i < 4; ++i) {
          float fsb = __shfl(fs, ((lane >> 4) << 2) + i);
#pragma unroll
          for (int dn = 0; dn < 4; ++dn) oacc[dn][i] *= fsb;
        }
        // pack PV A-frags: kappa = kss*32 + (j<4 ? 4g+j : 16+4g+(j-4))
        bf16x8 pa[2];
#pragma unroll
        for (int kss = 0; kss < 2; ++kss) {
          bf16x8 t;
#pragma unroll
          for (int j = 0; j < 4; ++j) t[j] = (bf16)sc[2 * kss][j];
#pragma unroll
          for (int j = 0; j < 4; ++j) t[4 + j] = (bf16)sc[2 * kss + 1][j];
          pa[kss] = t;
        }
        // PV: vb B-frag k = g*8+j with same kappa mapping; two b64 reads each
        __builtin_amdgcn_s_setprio(1);
#pragma unroll
        for (int kss = 0; kss < 2; ++kss) {
#pragma unroll
          for (int dn = 0; dn < 4; ++dn) {
            const int d = dn * 16 + c;
            const char* vrow = (const char*)Vs[cur] + d * 128;
            const int off = 8 * (g & 1);
            bf16x4 lo = *(const bf16x4*)(vrow + (((4 * kss + (g >> 1)) ^ (d & 7)) << 4) + off);
            bf16x4 hi = *(const bf16x4*)(vrow + (((4 * kss + 2 + (g >> 1)) ^ (d & 7)) << 4) + off);
            bf16x8 vb;
#pragma unroll
            for (int j = 0; j < 4; ++j) { vb[j] = lo[j]; vb[4 + j] = hi[j]; }
            oacc[dn] = mfma16(pa[kss], vb, oacc[dn]);
          }
        }
        __builtin_amdgcn_s_setprio(0);
      }
      __builtin_amdgcn_sched_barrier(0);
      __builtin_amdgcn_s_barrier();  // readers done before next-tile overwrite
      __builtin_amdgcn_sched_barrier(0);
    }
    // epilogue: normalize, store bf16 [8192][1024]
    float inv = __builtin_amdgcn_rcpf(lrun);  // lane q = qlow + c
#pragma unroll
    for (int i = 0; i < 4; ++i) {
      float invb = __shfl(inv, ((lane >> 4) << 2) + i);
      size_t row = (size_t)(b * 2048 + qlow + 4 * g + i);
#pragma unroll
      for (int dn = 0; dn < 4; ++dn)
        attn_out[row * 1024 + h * 64 + dn * 16 + c] = (bf16)(oacc[dn][i] * invb);
    }
  }
#undef STAGE
}

// ---------------- launch ----------------
extern "C" void kernel_launch(void* const* d_in, const int* in_sizes, int n_in,
                              void* d_out, int out_size, void* d_ws, size_t ws_size,
                              hipStream_t stream) {
  const float* x  = (const float*)d_in[0];
  const float* Wq = (const float*)d_in[1];
  const float* Wk = (const float*)d_in[2];
  const float* Wv = (const float*)d_in[3];
  const float* Wo = (const float*)d_in[4];
  const float* bo = (const float*)d_in[5];
  float* out = (float*)d_out;
  char* ws = (char*)d_ws;

  bf16* Xb    = (bf16*)(ws);
  bf16* WqkvT = (bf16*)(ws + 16777216);
  bf16* WoT   = (bf16*)(ws + 23068672);
  bf16* QKV   = (bf16*)(ws + 25165824);
  bf16* VT    = (bf16*)(ws + 75497472);
  bf16* AttnO = (bf16*)(ws + 92274688);

  pack_x_kernel<<<8192, 256, 0, stream>>>(x, Xb);
  pack_wqkv_kernel<<<12288, 256, 0, stream>>>(Wq, Wk, Wv, WqkvT);
  pack_wo_kernel<<<4096, 256, 0, stream>>>(Wo, WoT);
  gemm_bt_kernel<false><<<dim3(24, 64), 256, 0, stream>>>(Xb, WqkvT, QKV, nullptr, nullptr,
                                                          8192, 3072, 1024);
  transpose_v_kernel<<<dim3(32, 64), 256, 0, stream>>>(QKV, VT);
  attn_kernel<<<512, 512, 0, stream>>>(QKV, VT, AttnO);
  gemm_bt_kernel<true><<<dim3(8, 64), 256, 0, stream>>>(AttnO, WoT, nullptr, out, bo,
                                                        8192, 1024, 1024);
}

// Round 7
// 197.372 us; speedup vs baseline: 1.7961x; 1.0989x over previous
//
#include <hip/hip_runtime.h>

// B=4, S=2048, D=1024, H=16, HS=64. Full bf16-MFMA pipeline.
// Workspace layout (needs ~104 MiB):
//   Xb     @ 0         : x as bf16            [8192][1024]   16 MiB
//   WqkvT  @ 16777216  : qkv weights B^T bf16 [3072][1024]    6 MiB
//   WoT    @ 23068672  : Wo^T bf16            [1024][1024]    2 MiB
//   QKV    @ 25165824  : Q|K|V bf16           [8192][3072]   48 MiB
//   VT     @ 75497472  : V^T bf16             [64bh][64][2048] 16 MiB
//   AttnO  @ 92274688  : attention out bf16   [8192][1024]   16 MiB

typedef __bf16 bf16;
typedef bf16 bf16x8 __attribute__((ext_vector_type(8)));
typedef bf16 bf16x4 __attribute__((ext_vector_type(4)));
typedef float f32x4 __attribute__((ext_vector_type(4)));

__device__ __forceinline__ void gload16(const void* gsrc, void* ldst) {
  __builtin_amdgcn_global_load_lds(
      (const __attribute__((address_space(1))) unsigned int*)gsrc,
      (__attribute__((address_space(3))) unsigned int*)ldst, 16, 0, 0);
}

__device__ __forceinline__ f32x4 mfma16(bf16x8 a, bf16x8 b, f32x4 c) {
  return __builtin_amdgcn_mfma_f32_16x16x32_bf16(a, b, c, 0, 0, 0);
}

// ---------------- pack kernels ----------------
__global__ __launch_bounds__(256) void pack_x_kernel(const float* __restrict__ x,
                                                     bf16* __restrict__ xb) {
  int i = (blockIdx.x * 256 + threadIdx.x) * 4;  // grid sized exactly
  float4 v = *(const float4*)(x + i);
  bf16x4 o;
  o[0] = (bf16)v.x; o[1] = (bf16)v.y; o[2] = (bf16)v.z; o[3] = (bf16)v.w;
  *(bf16x4*)(xb + i) = o;
}

// WT[n][k] = W{q,k,v}[h = (n%1024)/64][k][e = n%64], n in [0,3072)
__global__ __launch_bounds__(256) void pack_wqkv_kernel(const float* __restrict__ Wq,
                                                        const float* __restrict__ Wk,
                                                        const float* __restrict__ Wv,
                                                        bf16* __restrict__ WT) {
  int idx = blockIdx.x * 256 + threadIdx.x;  // 0..3145727
  int n = idx >> 10, k = idx & 1023;
  int sel = n >> 10, nn = n & 1023;
  const float* W = (sel == 0) ? Wq : (sel == 1 ? Wk : Wv);
  int h = nn >> 6, e = nn & 63;
  WT[(size_t)n * 1024 + k] = (bf16)W[h * 65536 + k * 64 + e];
}

// WoT[n][k] = Wo[k][n]
__global__ __launch_bounds__(256) void pack_wo_kernel(const float* __restrict__ Wo,
                                                      bf16* __restrict__ WoT) {
  int idx = blockIdx.x * 256 + threadIdx.x;  // 0..1048575
  int n = idx >> 10, k = idx & 1023;
  WoT[idx] = (bf16)Wo[k * 1024 + n];
}

// ---------------- GEMM: C[M][N] = A[M][K] * BT[N][K]^T ----------------
// 128x128 tile, BK=32, 4 waves (2x2), each wave 64x64 (4x4 frags of 16x16x32).
template <bool F32OUT>
__global__ __launch_bounds__(256) void gemm_bt_kernel(const bf16* __restrict__ A,
                                                      const bf16* __restrict__ BT,
                                                      bf16* __restrict__ Cb,
                                                      float* __restrict__ Cf,
                                                      const float* __restrict__ bias,
                                                      int M, int N, int K) {
  __shared__ bf16 As[128 * 32];
  __shared__ bf16 Bs[128 * 32];
  const int tid = threadIdx.x, lane = tid & 63, wave = tid >> 6;
  const int g = lane >> 4, c = lane & 15;
  // bijective XCD swizzle (grid sizes are multiples of 8)
  const int nx = gridDim.x;
  const int nwg = nx * gridDim.y;
  const int bid = blockIdx.y * nx + blockIdx.x;
  const int swz = (bid & 7) * (nwg >> 3) + (bid >> 3);
  const int m0 = (swz / nx) * 128, n0 = (swz % nx) * 128;
  const int wr = wave >> 1, wc = wave & 1;

  f32x4 acc[4][4] = {};
  for (int k0 = 0; k0 < K; k0 += 32) {
#pragma unroll
    for (int t = 0; t < 2; ++t) {
      int o = t * 4096 + wave * 1024 + lane * 16;  // byte offset in 8KB tile
      int row = o >> 6, kb = (o & 63) >> 1;        // row, k-elem within BK
      gload16(A + (size_t)(m0 + row) * K + k0 + kb, (char*)As + o);
      gload16(BT + (size_t)(n0 + row) * K + k0 + kb, (char*)Bs + o);
    }
    __syncthreads();
    bf16x8 af[4], bfr[4];
#pragma unroll
    for (int m = 0; m < 4; ++m)
      af[m] = *(const bf16x8*)((const char*)As + (wr * 64 + m * 16 + c) * 64 + g * 16);
#pragma unroll
    for (int n = 0; n < 4; ++n)
      bfr[n] = *(const bf16x8*)((const char*)Bs + (wc * 64 + n * 16 + c) * 64 + g * 16);
#pragma unroll
    for (int m = 0; m < 4; ++m)
#pragma unroll
      for (int n = 0; n < 4; ++n)
        acc[m][n] = mfma16(af[m], bfr[n], acc[m][n]);
    __syncthreads();
  }
#pragma unroll
  for (int m = 0; m < 4; ++m)
#pragma unroll
    for (int n = 0; n < 4; ++n)
#pragma unroll
      for (int i = 0; i < 4; ++i) {
        int row = m0 + wr * 64 + m * 16 + g * 4 + i;
        int col = n0 + wc * 64 + n * 16 + c;
        if (F32OUT)
          Cf[(size_t)row * N + col] = acc[m][n][i] + bias[col];
        else
          Cb[(size_t)row * N + col] = (bf16)acc[m][n][i];
      }
}

// ---------------- V transpose: VT[bh][d][s] = V[b,s,h,d] ----------------
// 64x64 tile per block; 512 bf16x8 chunks per side -> 2 iterations per thread.
__global__ __launch_bounds__(256) void transpose_v_kernel(const bf16* __restrict__ qkv,
                                                          bf16* __restrict__ vt) {
  __shared__ bf16 tl[64][72];  // stride 144B keeps 16B alignment for b128 stores
  const int tid = threadIdx.x;
  const int st = blockIdx.x, bh = blockIdx.y;
  const int b = bh >> 4, h = bh & 15;
#pragma unroll
  for (int it = 0; it < 2; ++it) {
    int idx = it * 256 + tid;          // 0..511
    int sl = idx >> 3, ch = idx & 7;   // sl 0..63 (s row), ch 0..7 (d chunk)
    bf16x8 v = *(const bf16x8*)(qkv + (size_t)(b * 2048 + st * 64 + sl) * 3072 + 2048 + h * 64 + ch * 8);
    *(bf16x8*)&tl[sl][ch * 8] = v;
  }
  __syncthreads();
#pragma unroll
  for (int it = 0; it < 2; ++it) {
    int idx = it * 256 + tid;
    int d = idx >> 3, s8 = idx & 7;    // d 0..63, s chunk 0..7
    bf16x8 o;
#pragma unroll
    for (int j = 0; j < 8; ++j) o[j] = tl[s8 * 8 + j][d];
    *(bf16x8*)(vt + ((size_t)bh * 64 + d) * 2048 + st * 64 + s8 * 8) = o;
  }
}

// ---------------- causal flash attention ----------------
// Grid = 512 blocks x 512 threads (8 waves, 16 q-rows/wave), KVBLK=128.
// bh-major XCD mapping: xcd=bid&7, bh=(bid>>6)*8+xcd, x=(bid>>3)&7 -> all 8
// qt-blocks of one bh land on ONE XCD, making its K/V (512KB) L2-resident
// (8 bh x 512KB = 4MB = per-XCD L2). Block processes qt=x then qt=15-x:
// (x+1)+(16-x) = 17 uniform K-tiles. Double-buffered staging (4 loads/thread
// per tile), counted vmcnt. Swapped QK^T (mfma(K,Q)): per-lane softmax (q=c),
// in-lane PV A-frags, row-sum l via ones-MFMA directly in oacc layout.
__global__ __launch_bounds__(512, 4) void attn_kernel(const bf16* __restrict__ qkv,
                                                      const bf16* __restrict__ vt,
                                                      bf16* __restrict__ attn_out) {
  __shared__ bf16 Ks[2][128 * 64];   // [key][hd], chunk-swizzled, 16KB each
  __shared__ bf16 Vs[2][64 * 128];   // [d][key], chunk-swizzled, 16KB each
  const int tid = threadIdx.x, lane = tid & 63, wave = tid >> 6;
  const int g = lane >> 4, c = lane & 15;
  const int bid = blockIdx.x;
  const int xcd = bid & 7;
  const int x = (bid >> 3) & 7;
  const int bh = (bid >> 6) * 8 + xcd;
  const int b = bh >> 4, h = bh & 15;
  const float SCL = 0.125f * 1.4426950408889634f;  // log2(e) * scale

  bf16x8 ones;
#pragma unroll
  for (int j = 0; j < 8; ++j) ones[j] = (bf16)1.0f;

#define STAGE(KT, BUF)                                                                    \
  do {                                                                                    \
    _Pragma("unroll") for (int t2 = 0; t2 < 2; ++t2) {                                    \
      int o = t2 * 8192 + wave * 1024 + lane * 16; /* 0..16383 */                         \
      int rK = o >> 7, chK = (((o & 127) >> 4) ^ (rK & 7));                               \
      gload16((const char*)qkv +                                                          \
                  ((size_t)(b * 2048 + (KT)*128 + rK) * 3072 + 1024 + h * 64) * 2 +       \
                  (chK << 4),                                                             \
              (char*)Ks[BUF] + o);                                                        \
      int rV = o >> 8, chV = (((o & 255) >> 4) ^ (rV & 7));                               \
      gload16((const char*)vt + (((size_t)bh * 64 + rV) * 2048 + (KT)*128) * 2 +          \
                  (chV << 4),                                                             \
              (char*)Vs[BUF] + o);                                                        \
    }                                                                                     \
  } while (0)

#pragma unroll 1
  for (int ph = 0; ph < 2; ++ph) {
    const int qt = ph ? (15 - x) : x;
    const int qlow = qt * 128 + wave * 16;  // lowest q row of this wave

    bf16x8 qf[2];
#pragma unroll
    for (int kk = 0; kk < 2; ++kk) {
      size_t row = (size_t)(b * 2048 + qlow + c);
      qf[kk] = *(const bf16x8*)(qkv + row * 3072 + h * 64 + kk * 32 + g * 8);
    }

    f32x4 oacc[4] = {};
    f32x4 lacc = {};        // row-sums, oacc layout (q = qlow + 4g+i)
    float mrun = -3.0e38f;  // per-lane: q = qlow + c

    const int nkt = qt + 1;
    STAGE(0, 0);  // prologue
    for (int kt = 0; kt < nkt; ++kt) {
      const int cur = kt & 1;
      if (kt + 1 < nkt) {
        STAGE(kt + 1, cur ^ 1);
        asm volatile("s_waitcnt vmcnt(4)" ::: "memory");  // current tile landed
      } else {
        asm volatile("s_waitcnt vmcnt(0)" ::: "memory");
      }
      __builtin_amdgcn_sched_barrier(0);
      __builtin_amdgcn_s_barrier();
      __builtin_amdgcn_sched_barrier(0);
      // QK^T swapped: sc[n] holds S[key = kt*128+n*16+4g+i][q = qlow+c]
      f32x4 sc[8] = {};
      __builtin_amdgcn_s_setprio(1);
#pragma unroll
      for (int n = 0; n < 8; ++n) {
        int key = n * 16 + c;
#pragma unroll
        for (int kk = 0; kk < 2; ++kk) {
          bf16x8 kf = *(const bf16x8*)((const char*)Ks[cur] + key * 128 +
                                       (((kk * 4 + g) ^ (key & 7)) << 4));
          sc[n] = mfma16(kf, qf[kk], sc[n]);
        }
      }
      __builtin_amdgcn_s_setprio(0);
      const int q = qlow + c;
      if (kt == qt) {  // diagonal tile: causal mask
#pragma unroll
        for (int n = 0; n < 8; ++n)
#pragma unroll
          for (int i = 0; i < 4; ++i)
            sc[n][i] = ((kt * 128 + n * 16 + 4 * g + i) <= q) ? sc[n][i] : -3.0e38f;
      }
      float vmax = -3.0e38f;
#pragma unroll
      for (int n = 0; n < 8; ++n)
#pragma unroll
        for (int i = 0; i < 4; ++i) vmax = fmaxf(vmax, sc[n][i]);
      vmax = fmaxf(vmax, __shfl_xor(vmax, 16));
      vmax = fmaxf(vmax, __shfl_xor(vmax, 32));
      const float mnew = fmaxf(mrun, vmax * SCL);
      const float fs = __builtin_amdgcn_exp2f(mrun - mnew);
      mrun = mnew;
#pragma unroll
      for (int n = 0; n < 8; ++n)
#pragma unroll
        for (int i = 0; i < 4; ++i)
          sc[n][i] = __builtin_amdgcn_exp2f(fmaf(sc[n][i], SCL, -mnew));
      // broadcast fs from softmax layout (q=c) to oacc layout (q=4g+i)
#pragma unroll
      for (int i = 0; i < 4; ++i) {
        float fsb = __shfl(fs, ((lane >> 4) << 2) + i);
        lacc[i] *= fsb;
#pragma unroll
        for (int dn = 0; dn < 4; ++dn) oacc[dn][i] *= fsb;
      }
      // pack PV A-frags: key = kss*32 + (j<4 ? 4g+j : 16+4g+(j-4))
      bf16x8 pa[4];
#pragma unroll
      for (int kss = 0; kss < 4; ++kss) {
        bf16x8 t;
#pragma unroll
        for (int j = 0; j < 4; ++j) t[j] = (bf16)sc[2 * kss][j];
#pragma unroll
        for (int j = 0; j < 4; ++j) t[4 + j] = (bf16)sc[2 * kss + 1][j];
        pa[kss] = t;
      }
      // PV + row-sum via ones-MFMA; vb B-frag k = g*8+j, same kappa mapping
      __builtin_amdgcn_s_setprio(1);
#pragma unroll
      for (int kss = 0; kss < 4; ++kss) {
        lacc = mfma16(pa[kss], ones, lacc);
#pragma unroll
        for (int dn = 0; dn < 4; ++dn) {
          const int d = dn * 16 + c;
          const char* vrow = (const char*)Vs[cur] + d * 256;
          const int off = 8 * (g & 1);
          bf16x4 lo = *(const bf16x4*)(vrow + (((4 * kss + (g >> 1)) ^ (d & 7)) << 4) + off);
          bf16x4 hi = *(const bf16x4*)(vrow + (((4 * kss + 2 + (g >> 1)) ^ (d & 7)) << 4) + off);
          bf16x8 vb;
#pragma unroll
          for (int j = 0; j < 4; ++j) { vb[j] = lo[j]; vb[4 + j] = hi[j]; }
          oacc[dn] = mfma16(pa[kss], vb, oacc[dn]);
        }
      }
      __builtin_amdgcn_s_setprio(0);
      __builtin_amdgcn_sched_barrier(0);
      __builtin_amdgcn_s_barrier();  // readers done before next-tile overwrite
      __builtin_amdgcn_sched_barrier(0);
    }
    // epilogue: normalize, store bf16 [8192][1024]
#pragma unroll
    for (int i = 0; i < 4; ++i) {
      float inv = __builtin_amdgcn_rcpf(lacc[i]);
      size_t row = (size_t)(b * 2048 + qlow + 4 * g + i);
#pragma unroll
      for (int dn = 0; dn < 4; ++dn)
        attn_out[row * 1024 + h * 64 + dn * 16 + c] = (bf16)(oacc[dn][i] * inv);
    }
  }
#undef STAGE
}

// ---------------- launch ----------------
extern "C" void kernel_launch(void* const* d_in, const int* in_sizes, int n_in,
                              void* d_out, int out_size, void* d_ws, size_t ws_size,
                              hipStream_t stream) {
  const float* x  = (const float*)d_in[0];
  const float* Wq = (const float*)d_in[1];
  const float* Wk = (const float*)d_in[2];
  const float* Wv = (const float*)d_in[3];
  const float* Wo = (const float*)d_in[4];
  const float* bo = (const float*)d_in[5];
  float* out = (float*)d_out;
  char* ws = (char*)d_ws;

  bf16* Xb    = (bf16*)(ws);
  bf16* WqkvT = (bf16*)(ws + 16777216);
  bf16* WoT   = (bf16*)(ws + 23068672);
  bf16* QKV   = (bf16*)(ws + 25165824);
  bf16* VT    = (bf16*)(ws + 75497472);
  bf16* AttnO = (bf16*)(ws + 92274688);

  pack_x_kernel<<<8192, 256, 0, stream>>>(x, Xb);
  pack_wqkv_kernel<<<12288, 256, 0, stream>>>(Wq, Wk, Wv, WqkvT);
  pack_wo_kernel<<<4096, 256, 0, stream>>>(Wo, WoT);
  gemm_bt_kernel<false><<<dim3(24, 64), 256, 0, stream>>>(Xb, WqkvT, QKV, nullptr, nullptr,
                                                          8192, 3072, 1024);
  transpose_v_kernel<<<dim3(32, 64), 256, 0, stream>>>(QKV, VT);
  attn_kernel<<<512, 512, 0, stream>>>(QKV, VT, AttnO);
  gemm_bt_kernel<true><<<dim3(8, 64), 256, 0, stream>>>(AttnO, WoT, nullptr, out, bo,
                                                        8192, 1024, 1024);
}

// Round 8
// 196.178 us; speedup vs baseline: 1.8071x; 1.0061x over previous
//
#include <hip/hip_runtime.h>

// B=4, S=2048, D=1024, H=16, HS=64. Full bf16-MFMA pipeline.
// Workspace layout (needs ~104 MiB):
//   Xb     @ 0         : x as bf16            [8192][1024]   16 MiB
//   WqkvT  @ 16777216  : qkv weights B^T bf16 [3072][1024]    6 MiB
//   WoT    @ 23068672  : Wo^T bf16            [1024][1024]    2 MiB
//   QKV    @ 25165824  : Q|K|V bf16           [8192][3072]   48 MiB
//   VT     @ 75497472  : V^T bf16             [64bh][64][2048] 16 MiB
//   AttnO  @ 92274688  : attention out bf16   [8192][1024]   16 MiB

typedef __bf16 bf16;
typedef bf16 bf16x8 __attribute__((ext_vector_type(8)));
typedef bf16 bf16x4 __attribute__((ext_vector_type(4)));
typedef float f32x4 __attribute__((ext_vector_type(4)));

__device__ __forceinline__ void gload16(const void* gsrc, void* ldst) {
  __builtin_amdgcn_global_load_lds(
      (const __attribute__((address_space(1))) unsigned int*)gsrc,
      (__attribute__((address_space(3))) unsigned int*)ldst, 16, 0, 0);
}

__device__ __forceinline__ f32x4 mfma16(bf16x8 a, bf16x8 b, f32x4 c) {
  return __builtin_amdgcn_mfma_f32_16x16x32_bf16(a, b, c, 0, 0, 0);
}

// ---------------- pack kernels ----------------
__global__ __launch_bounds__(256) void pack_x_kernel(const float* __restrict__ x,
                                                     bf16* __restrict__ xb) {
  int i = (blockIdx.x * 256 + threadIdx.x) * 4;  // grid sized exactly
  float4 v = *(const float4*)(x + i);
  bf16x4 o;
  o[0] = (bf16)v.x; o[1] = (bf16)v.y; o[2] = (bf16)v.z; o[3] = (bf16)v.w;
  *(bf16x4*)(xb + i) = o;
}

// WT[n][k] = W{q,k,v}[h = (n%1024)/64][k][e = n%64], n in [0,3072)
__global__ __launch_bounds__(256) void pack_wqkv_kernel(const float* __restrict__ Wq,
                                                        const float* __restrict__ Wk,
                                                        const float* __restrict__ Wv,
                                                        bf16* __restrict__ WT) {
  int idx = blockIdx.x * 256 + threadIdx.x;  // 0..3145727
  int n = idx >> 10, k = idx & 1023;
  int sel = n >> 10, nn = n & 1023;
  const float* W = (sel == 0) ? Wq : (sel == 1 ? Wk : Wv);
  int h = nn >> 6, e = nn & 63;
  WT[(size_t)n * 1024 + k] = (bf16)W[h * 65536 + k * 64 + e];
}

// WoT[n][k] = Wo[k][n]
__global__ __launch_bounds__(256) void pack_wo_kernel(const float* __restrict__ Wo,
                                                      bf16* __restrict__ WoT) {
  int idx = blockIdx.x * 256 + threadIdx.x;  // 0..1048575
  int n = idx >> 10, k = idx & 1023;
  WoT[idx] = (bf16)Wo[k * 1024 + n];
}

// ---------------- GEMM v2: C[M][N] = A[M][K] * BT[N][K]^T ----------------
// 128x128 tile, BK=64 as two 32-k phases; K=1024 -> 32 phases. 512 threads =
// 8 waves (2M x 4N), per-wave 64x32 output (4m x 2n frags). LDS 64KB:
// [2 buf][2 kh] regions of A(8KB)+B(8KB). Pipeline: phase p stages the region
// read at phase p+3 (2 K-tiles ahead); that slot's previous reader finished at
// p-1 (barrier-separated) -> no overwrite hazard. Steady-state vmcnt(4), one
// s_barrier per phase, never a full drain in the main loop. Both-sides XOR
// chunk swizzle (pre-swizzled global source, XOR'd ds_read). T5 setprio.
template <bool F32OUT>
__global__ __launch_bounds__(512, 4) void gemm3_kernel(const bf16* __restrict__ A,
                                                       const bf16* __restrict__ BT,
                                                       bf16* __restrict__ Cb,
                                                       float* __restrict__ Cf,
                                                       const float* __restrict__ bias,
                                                       int N, int K, int NT) {
  __shared__ bf16 As[2][2][128 * 32];  // [buf][kh][row][k] 8KB regions
  __shared__ bf16 Bs[2][2][128 * 32];
  const int tid = threadIdx.x, lane = tid & 63, wave = tid >> 6;
  const int g = lane >> 4, c = lane & 15;
  const int wr = wave >> 2, wc = wave & 3;  // 2M x 4N waves
  const int bid = blockIdx.x;
  const int q8 = gridDim.x >> 3;  // grid divisible by 8
  const int swz = (bid & 7) * q8 + (bid >> 3);
  const int m0 = (swz / NT) * 128, n0 = (swz % NT) * 128;

  const int r_s = tid >> 2;                       // staged row 0..127
  const int chs = (tid & 3) ^ ((r_s >> 1) & 3);   // pre-swizzled source chunk
  const int chsw = (g ^ ((c >> 1) & 3)) << 4;     // read chunk byte offset

#define STAGE3(P)                                                                   \
  do {                                                                             \
    const int t_ = (P) >> 1, kh_ = (P)&1, bf_ = t_ & 1;                            \
    const int kofs = t_ * 64 + kh_ * 32 + chs * 8;                                 \
    gload16(A + (size_t)(m0 + r_s) * K + kofs, (char*)&As[bf_][kh_][0] + tid * 16); \
    gload16(BT + (size_t)(n0 + r_s) * K + kofs, (char*)&Bs[bf_][kh_][0] + tid * 16); \
  } while (0)

  f32x4 acc[4][2] = {};
  STAGE3(0);
  STAGE3(1);
  STAGE3(2);
  asm volatile("s_waitcnt vmcnt(4)" ::: "memory");  // region 0 landed
  __builtin_amdgcn_sched_barrier(0);
  __builtin_amdgcn_s_barrier();
  __builtin_amdgcn_sched_barrier(0);

#pragma unroll 1
  for (int p = 0; p < 32; ++p) {  // K/32 phases (K=1024)
    if (p <= 28) STAGE3(p + 3);
    const char* abase = (const char*)&As[(p >> 1) & 1][p & 1][0];
    const char* bbase = (const char*)&Bs[(p >> 1) & 1][p & 1][0];
    bf16x8 af[4], bfr[2];
#pragma unroll
    for (int m = 0; m < 4; ++m)
      af[m] = *(const bf16x8*)(abase + (wr * 64 + m * 16 + c) * 64 + chsw);
#pragma unroll
    for (int n = 0; n < 2; ++n)
      bfr[n] = *(const bf16x8*)(bbase + (wc * 32 + n * 16 + c) * 64 + chsw);
    asm volatile("s_waitcnt lgkmcnt(0)" ::: "memory");
    __builtin_amdgcn_sched_barrier(0);
    __builtin_amdgcn_s_setprio(1);
#pragma unroll
    for (int m = 0; m < 4; ++m)
#pragma unroll
      for (int n = 0; n < 2; ++n)
        acc[m][n] = mfma16(af[m], bfr[n], acc[m][n]);
    __builtin_amdgcn_s_setprio(0);
    __builtin_amdgcn_sched_barrier(0);
    if (p <= 28) {
      asm volatile("s_waitcnt vmcnt(4)" ::: "memory");  // region p+1 landed
    } else if (p == 29) {
      asm volatile("s_waitcnt vmcnt(2)" ::: "memory");
    } else if (p == 30) {
      asm volatile("s_waitcnt vmcnt(0)" ::: "memory");
    }
    if (p < 31) {
      __builtin_amdgcn_sched_barrier(0);
      __builtin_amdgcn_s_barrier();
      __builtin_amdgcn_sched_barrier(0);
    }
  }
#undef STAGE3
  // epilogue (mapping identical to verified r1 kernel)
#pragma unroll
  for (int m = 0; m < 4; ++m)
#pragma unroll
    for (int n = 0; n < 2; ++n)
#pragma unroll
      for (int i = 0; i < 4; ++i) {
        int row = m0 + wr * 64 + m * 16 + g * 4 + i;
        int col = n0 + wc * 32 + n * 16 + c;
        if (F32OUT)
          Cf[(size_t)row * N + col] = acc[m][n][i] + bias[col];
        else
          Cb[(size_t)row * N + col] = (bf16)acc[m][n][i];
      }
}

// ---------------- V transpose: VT[bh][d][s] = V[b,s,h,d] ----------------
// 64x64 tile per block; 512 bf16x8 chunks per side -> 2 iterations per thread.
__global__ __launch_bounds__(256) void transpose_v_kernel(const bf16* __restrict__ qkv,
                                                          bf16* __restrict__ vt) {
  __shared__ bf16 tl[64][72];  // stride 144B keeps 16B alignment for b128 stores
  const int tid = threadIdx.x;
  const int st = blockIdx.x, bh = blockIdx.y;
  const int b = bh >> 4, h = bh & 15;
#pragma unroll
  for (int it = 0; it < 2; ++it) {
    int idx = it * 256 + tid;          // 0..511
    int sl = idx >> 3, ch = idx & 7;   // sl 0..63 (s row), ch 0..7 (d chunk)
    bf16x8 v = *(const bf16x8*)(qkv + (size_t)(b * 2048 + st * 64 + sl) * 3072 + 2048 + h * 64 + ch * 8);
    *(bf16x8*)&tl[sl][ch * 8] = v;
  }
  __syncthreads();
#pragma unroll
  for (int it = 0; it < 2; ++it) {
    int idx = it * 256 + tid;
    int d = idx >> 3, s8 = idx & 7;    // d 0..63, s chunk 0..7
    bf16x8 o;
#pragma unroll
    for (int j = 0; j < 8; ++j) o[j] = tl[s8 * 8 + j][d];
    *(bf16x8*)(vt + ((size_t)bh * 64 + d) * 2048 + st * 64 + s8 * 8) = o;
  }
}

// ---------------- causal flash attention ----------------
// Grid = 512 blocks x 512 threads (8 waves, 16 q-rows/wave), KVBLK=128.
// bh-major XCD mapping: xcd=bid&7, bh=(bid>>6)*8+xcd, x=(bid>>3)&7 -> all 8
// qt-blocks of one bh land on ONE XCD, making its K/V (512KB) L2-resident
// (8 bh x 512KB = 4MB = per-XCD L2). Block processes qt=x then qt=15-x:
// (x+1)+(16-x) = 17 uniform K-tiles. Double-buffered staging (4 loads/thread
// per tile), counted vmcnt. Swapped QK^T (mfma(K,Q)): per-lane softmax (q=c),
// in-lane PV A-frags, row-sum l via ones-MFMA directly in oacc layout.
__global__ __launch_bounds__(512, 4) void attn_kernel(const bf16* __restrict__ qkv,
                                                      const bf16* __restrict__ vt,
                                                      bf16* __restrict__ attn_out) {
  __shared__ bf16 Ks[2][128 * 64];   // [key][hd], chunk-swizzled, 16KB each
  __shared__ bf16 Vs[2][64 * 128];   // [d][key], chunk-swizzled, 16KB each
  const int tid = threadIdx.x, lane = tid & 63, wave = tid >> 6;
  const int g = lane >> 4, c = lane & 15;
  const int bid = blockIdx.x;
  const int xcd = bid & 7;
  const int x = (bid >> 3) & 7;
  const int bh = (bid >> 6) * 8 + xcd;
  const int b = bh >> 4, h = bh & 15;
  const float SCL = 0.125f * 1.4426950408889634f;  // log2(e) * scale

  bf16x8 ones;
#pragma unroll
  for (int j = 0; j < 8; ++j) ones[j] = (bf16)1.0f;

#define STAGE(KT, BUF)                                                                    \
  do {                                                                                    \
    _Pragma("unroll") for (int t2 = 0; t2 < 2; ++t2) {                                    \
      int o = t2 * 8192 + wave * 1024 + lane * 16; /* 0..16383 */                         \
      int rK = o >> 7, chK = (((o & 127) >> 4) ^ (rK & 7));                               \
      gload16((const char*)qkv +                                                          \
                  ((size_t)(b * 2048 + (KT)*128 + rK) * 3072 + 1024 + h * 64) * 2 +       \
                  (chK << 4),                                                             \
              (char*)Ks[BUF] + o);                                                        \
      int rV = o >> 8, chV = (((o & 255) >> 4) ^ (rV & 7));                               \
      gload16((const char*)vt + (((size_t)bh * 64 + rV) * 2048 + (KT)*128) * 2 +          \
                  (chV << 4),                                                             \
              (char*)Vs[BUF] + o);                                                        \
    }                                                                                     \
  } while (0)

#pragma unroll 1
  for (int ph = 0; ph < 2; ++ph) {
    const int qt = ph ? (15 - x) : x;
    const int qlow = qt * 128 + wave * 16;  // lowest q row of this wave

    bf16x8 qf[2];
#pragma unroll
    for (int kk = 0; kk < 2; ++kk) {
      size_t row = (size_t)(b * 2048 + qlow + c);
      qf[kk] = *(const bf16x8*)(qkv + row * 3072 + h * 64 + kk * 32 + g * 8);
    }

    f32x4 oacc[4] = {};
    f32x4 lacc = {};        // row-sums, oacc layout (q = qlow + 4g+i)
    float mrun = -3.0e38f;  // per-lane: q = qlow + c

    const int nkt = qt + 1;
    STAGE(0, 0);  // prologue
    for (int kt = 0; kt < nkt; ++kt) {
      const int cur = kt & 1;
      if (kt + 1 < nkt) {
        STAGE(kt + 1, cur ^ 1);
        asm volatile("s_waitcnt vmcnt(4)" ::: "memory");  // current tile landed
      } else {
        asm volatile("s_waitcnt vmcnt(0)" ::: "memory");
      }
      __builtin_amdgcn_sched_barrier(0);
      __builtin_amdgcn_s_barrier();
      __builtin_amdgcn_sched_barrier(0);
      // QK^T swapped: sc[n] holds S[key = kt*128+n*16+4g+i][q = qlow+c]
      f32x4 sc[8] = {};
      __builtin_amdgcn_s_setprio(1);
#pragma unroll
      for (int n = 0; n < 8; ++n) {
        int key = n * 16 + c;
#pragma unroll
        for (int kk = 0; kk < 2; ++kk) {
          bf16x8 kf = *(const bf16x8*)((const char*)Ks[cur] + key * 128 +
                                       (((kk * 4 + g) ^ (key & 7)) << 4));
          sc[n] = mfma16(kf, qf[kk], sc[n]);
        }
      }
      __builtin_amdgcn_s_setprio(0);
      const int q = qlow + c;
      if (kt == qt) {  // diagonal tile: causal mask
#pragma unroll
        for (int n = 0; n < 8; ++n)
#pragma unroll
          for (int i = 0; i < 4; ++i)
            sc[n][i] = ((kt * 128 + n * 16 + 4 * g + i) <= q) ? sc[n][i] : -3.0e38f;
      }
      float vmax = -3.0e38f;
#pragma unroll
      for (int n = 0; n < 8; ++n)
#pragma unroll
        for (int i = 0; i < 4; ++i) vmax = fmaxf(vmax, sc[n][i]);
      vmax = fmaxf(vmax, __shfl_xor(vmax, 16));
      vmax = fmaxf(vmax, __shfl_xor(vmax, 32));
      const float mnew = fmaxf(mrun, vmax * SCL);
      const float fs = __builtin_amdgcn_exp2f(mrun - mnew);
      mrun = mnew;
#pragma unroll
      for (int n = 0; n < 8; ++n)
#pragma unroll
        for (int i = 0; i < 4; ++i)
          sc[n][i] = __builtin_amdgcn_exp2f(fmaf(sc[n][i], SCL, -mnew));
      // broadcast fs from softmax layout (q=c) to oacc layout (q=4g+i)
#pragma unroll
      for (int i = 0; i < 4; ++i) {
        float fsb = __shfl(fs, ((lane >> 4) << 2) + i);
        lacc[i] *= fsb;
#pragma unroll
        for (int dn = 0; dn < 4; ++dn) oacc[dn][i] *= fsb;
      }
      // pack PV A-frags: key = kss*32 + (j<4 ? 4g+j : 16+4g+(j-4))
      bf16x8 pa[4];
#pragma unroll
      for (int kss = 0; kss < 4; ++kss) {
        bf16x8 t;
#pragma unroll
        for (int j = 0; j < 4; ++j) t[j] = (bf16)sc[2 * kss][j];
#pragma unroll
        for (int j = 0; j < 4; ++j) t[4 + j] = (bf16)sc[2 * kss + 1][j];
        pa[kss] = t;
      }
      // PV + row-sum via ones-MFMA; vb B-frag k = g*8+j, same kappa mapping
      __builtin_amdgcn_s_setprio(1);
#pragma unroll
      for (int kss = 0; kss < 4; ++kss) {
        lacc = mfma16(pa[kss], ones, lacc);
#pragma unroll
        for (int dn = 0; dn < 4; ++dn) {
          const int d = dn * 16 + c;
          const char* vrow = (const char*)Vs[cur] + d * 256;
          const int off = 8 * (g & 1);
          bf16x4 lo = *(const bf16x4*)(vrow + (((4 * kss + (g >> 1)) ^ (d & 7)) << 4) + off);
          bf16x4 hi = *(const bf16x4*)(vrow + (((4 * kss + 2 + (g >> 1)) ^ (d & 7)) << 4) + off);
          bf16x8 vb;
#pragma unroll
          for (int j = 0; j < 4; ++j) { vb[j] = lo[j]; vb[4 + j] = hi[j]; }
          oacc[dn] = mfma16(pa[kss], vb, oacc[dn]);
        }
      }
      __builtin_amdgcn_s_setprio(0);
      __builtin_amdgcn_sched_barrier(0);
      __builtin_amdgcn_s_barrier();  // readers done before next-tile overwrite
      __builtin_amdgcn_sched_barrier(0);
    }
    // epilogue: normalize, store bf16 [8192][1024]
#pragma unroll
    for (int i = 0; i < 4; ++i) {
      float inv = __builtin_amdgcn_rcpf(lacc[i]);
      size_t row = (size_t)(b * 2048 + qlow + 4 * g + i);
#pragma unroll
      for (int dn = 0; dn < 4; ++dn)
        attn_out[row * 1024 + h * 64 + dn * 16 + c] = (bf16)(oacc[dn][i] * inv);
    }
  }
#undef STAGE
}

// ---------------- launch ----------------
extern "C" void kernel_launch(void* const* d_in, const int* in_sizes, int n_in,
                              void* d_out, int out_size, void* d_ws, size_t ws_size,
                              hipStream_t stream) {
  const float* x  = (const float*)d_in[0];
  const float* Wq = (const float*)d_in[1];
  const float* Wk = (const float*)d_in[2];
  const float* Wv = (const float*)d_in[3];
  const float* Wo = (const float*)d_in[4];
  const float* bo = (const float*)d_in[5];
  float* out = (float*)d_out;
  char* ws = (char*)d_ws;

  bf16* Xb    = (bf16*)(ws);
  bf16* WqkvT = (bf16*)(ws + 16777216);
  bf16* WoT   = (bf16*)(ws + 23068672);
  bf16* QKV   = (bf16*)(ws + 25165824);
  bf16* VT    = (bf16*)(ws + 75497472);
  bf16* AttnO = (bf16*)(ws + 92274688);

  pack_x_kernel<<<8192, 256, 0, stream>>>(x, Xb);
  pack_wqkv_kernel<<<12288, 256, 0, stream>>>(Wq, Wk, Wv, WqkvT);
  pack_wo_kernel<<<4096, 256, 0, stream>>>(Wo, WoT);
  gemm3_kernel<false><<<1536, 512, 0, stream>>>(Xb, WqkvT, QKV, nullptr, nullptr,
                                                3072, 1024, 24);
  transpose_v_kernel<<<dim3(32, 64), 256, 0, stream>>>(QKV, VT);
  attn_kernel<<<512, 512, 0, stream>>>(QKV, VT, AttnO);
  gemm3_kernel<true><<<512, 512, 0, stream>>>(AttnO, WoT, nullptr, out, bo,
                                              1024, 1024, 8);
}

// Round 9
// 195.598 us; speedup vs baseline: 1.8124x; 1.0030x over previous
//
#include <hip/hip_runtime.h>

// B=4, S=2048, D=1024, H=16, HS=64. Full bf16-MFMA pipeline.
// Workspace layout (needs ~104 MiB):
//   Xb     @ 0         : x as bf16            [8192][1024]   16 MiB
//   WqkvT  @ 16777216  : qkv weights B^T bf16 [3072][1024]    6 MiB
//   WoT    @ 23068672  : Wo^T bf16            [1024][1024]    2 MiB
//   QKV    @ 25165824  : Q|K|V bf16           [8192][3072]   48 MiB
//   VT     @ 75497472  : V^T bf16             [64bh][64][2048] 16 MiB
//   AttnO  @ 92274688  : attention out bf16   [8192][1024]   16 MiB

typedef __bf16 bf16;
typedef bf16 bf16x8 __attribute__((ext_vector_type(8)));
typedef bf16 bf16x4 __attribute__((ext_vector_type(4)));
typedef float f32x4 __attribute__((ext_vector_type(4)));

__device__ __forceinline__ void gload16(const void* gsrc, void* ldst) {
  __builtin_amdgcn_global_load_lds(
      (const __attribute__((address_space(1))) unsigned int*)gsrc,
      (__attribute__((address_space(3))) unsigned int*)ldst, 16, 0, 0);
}

__device__ __forceinline__ f32x4 mfma16(bf16x8 a, bf16x8 b, f32x4 c) {
  return __builtin_amdgcn_mfma_f32_16x16x32_bf16(a, b, c, 0, 0, 0);
}

// ---------------- pack kernels ----------------
__global__ __launch_bounds__(256) void pack_x_kernel(const float* __restrict__ x,
                                                     bf16* __restrict__ xb) {
  int i = (blockIdx.x * 256 + threadIdx.x) * 4;  // grid sized exactly
  float4 v = *(const float4*)(x + i);
  bf16x4 o;
  o[0] = (bf16)v.x; o[1] = (bf16)v.y; o[2] = (bf16)v.z; o[3] = (bf16)v.w;
  *(bf16x4*)(xb + i) = o;
}

// WT[n][k] = W{q,k,v}[h = (n%1024)/64][k][e = n%64], n in [0,3072)
__global__ __launch_bounds__(256) void pack_wqkv_kernel(const float* __restrict__ Wq,
                                                        const float* __restrict__ Wk,
                                                        const float* __restrict__ Wv,
                                                        bf16* __restrict__ WT) {
  int idx = blockIdx.x * 256 + threadIdx.x;  // 0..3145727
  int n = idx >> 10, k = idx & 1023;
  int sel = n >> 10, nn = n & 1023;
  const float* W = (sel == 0) ? Wq : (sel == 1 ? Wk : Wv);
  int h = nn >> 6, e = nn & 63;
  WT[(size_t)n * 1024 + k] = (bf16)W[h * 65536 + k * 64 + e];
}

// WoT[n][k] = Wo[k][n]
__global__ __launch_bounds__(256) void pack_wo_kernel(const float* __restrict__ Wo,
                                                      bf16* __restrict__ WoT) {
  int idx = blockIdx.x * 256 + threadIdx.x;  // 0..1048575
  int n = idx >> 10, k = idx & 1023;
  WoT[idx] = (bf16)Wo[k * 1024 + n];
}

// ---------------- GEMM v2: C[M][N] = A[M][K] * BT[N][K]^T ----------------
// 128x128 tile, BK=64 as two 32-k phases; K=1024 -> 32 phases. 512 threads =
// 8 waves (2M x 4N), per-wave 64x32 output (4m x 2n frags). LDS 64KB:
// [2 buf][2 kh] regions of A(8KB)+B(8KB). Pipeline: phase p stages the region
// read at phase p+3; steady-state vmcnt(4), one s_barrier per phase, no full
// drain in the main loop. Both-sides XOR chunk swizzle. T5 setprio.
//
// Block->tile mapping (round-9 change): n-major per-XCD. xcd=bid&7 (XCD
// round-robin by dispatch index), local=bid>>3; m-tile = xcd*8 + (local&7),
// n-tile = local>>3. Each XCD owns an 8-m-row A panel (2MB, L2-resident for
// its entire run) and walks n slowly: each B tile is consumed by 8
// consecutive blocks; concurrent working set ~ 2MB A + 2MB B = L2. This
// converts the previous B-thrash (6MB B streamed per m-tile -> L3-BW-bound
// staging at ~9.6TB/s) into L2 hits. Requires M/128 == 64 (M=8192).
template <bool F32OUT>
__global__ __launch_bounds__(512, 4) void gemm3_kernel(const bf16* __restrict__ A,
                                                       const bf16* __restrict__ BT,
                                                       bf16* __restrict__ Cb,
                                                       float* __restrict__ Cf,
                                                       const float* __restrict__ bias,
                                                       int N, int K, int NT) {
  __shared__ bf16 As[2][2][128 * 32];  // [buf][kh][row][k] 8KB regions
  __shared__ bf16 Bs[2][2][128 * 32];
  const int tid = threadIdx.x, lane = tid & 63, wave = tid >> 6;
  const int g = lane >> 4, c = lane & 15;
  const int wr = wave >> 2, wc = wave & 3;  // 2M x 4N waves
  const int bid = blockIdx.x;
  const int xcd = bid & 7;
  const int local = bid >> 3;
  const int m0 = (xcd * 8 + (local & 7)) * 128;
  const int n0 = (local >> 3) * 128;
  (void)NT;

  const int r_s = tid >> 2;                       // staged row 0..127
  const int chs = (tid & 3) ^ ((r_s >> 1) & 3);   // pre-swizzled source chunk
  const int chsw = (g ^ ((c >> 1) & 3)) << 4;     // read chunk byte offset

#define STAGE3(P)                                                                   \
  do {                                                                             \
    const int t_ = (P) >> 1, kh_ = (P)&1, bf_ = t_ & 1;                            \
    const int kofs = t_ * 64 + kh_ * 32 + chs * 8;                                 \
    gload16(A + (size_t)(m0 + r_s) * K + kofs, (char*)&As[bf_][kh_][0] + tid * 16); \
    gload16(BT + (size_t)(n0 + r_s) * K + kofs, (char*)&Bs[bf_][kh_][0] + tid * 16); \
  } while (0)

  f32x4 acc[4][2] = {};
  STAGE3(0);
  STAGE3(1);
  STAGE3(2);
  asm volatile("s_waitcnt vmcnt(4)" ::: "memory");  // region 0 landed
  __builtin_amdgcn_sched_barrier(0);
  __builtin_amdgcn_s_barrier();
  __builtin_amdgcn_sched_barrier(0);

#pragma unroll 1
  for (int p = 0; p < 32; ++p) {  // K/32 phases (K=1024)
    if (p <= 28) STAGE3(p + 3);
    const char* abase = (const char*)&As[(p >> 1) & 1][p & 1][0];
    const char* bbase = (const char*)&Bs[(p >> 1) & 1][p & 1][0];
    bf16x8 af[4], bfr[2];
#pragma unroll
    for (int m = 0; m < 4; ++m)
      af[m] = *(const bf16x8*)(abase + (wr * 64 + m * 16 + c) * 64 + chsw);
#pragma unroll
    for (int n = 0; n < 2; ++n)
      bfr[n] = *(const bf16x8*)(bbase + (wc * 32 + n * 16 + c) * 64 + chsw);
    asm volatile("s_waitcnt lgkmcnt(0)" ::: "memory");
    __builtin_amdgcn_sched_barrier(0);
    __builtin_amdgcn_s_setprio(1);
#pragma unroll
    for (int m = 0; m < 4; ++m)
#pragma unroll
      for (int n = 0; n < 2; ++n)
        acc[m][n] = mfma16(af[m], bfr[n], acc[m][n]);
    __builtin_amdgcn_s_setprio(0);
    __builtin_amdgcn_sched_barrier(0);
    if (p <= 28) {
      asm volatile("s_waitcnt vmcnt(4)" ::: "memory");  // region p+1 landed
    } else if (p == 29) {
      asm volatile("s_waitcnt vmcnt(2)" ::: "memory");
    } else if (p == 30) {
      asm volatile("s_waitcnt vmcnt(0)" ::: "memory");
    }
    if (p < 31) {
      __builtin_amdgcn_sched_barrier(0);
      __builtin_amdgcn_s_barrier();
      __builtin_amdgcn_sched_barrier(0);
    }
  }
#undef STAGE3
  // epilogue (mapping identical to verified r1 kernel)
#pragma unroll
  for (int m = 0; m < 4; ++m)
#pragma unroll
    for (int n = 0; n < 2; ++n)
#pragma unroll
      for (int i = 0; i < 4; ++i) {
        int row = m0 + wr * 64 + m * 16 + g * 4 + i;
        int col = n0 + wc * 32 + n * 16 + c;
        if (F32OUT)
          Cf[(size_t)row * N + col] = acc[m][n][i] + bias[col];
        else
          Cb[(size_t)row * N + col] = (bf16)acc[m][n][i];
      }
}

// ---------------- V transpose: VT[bh][d][s] = V[b,s,h,d] ----------------
// 64x64 tile per block; 512 bf16x8 chunks per side -> 2 iterations per thread.
__global__ __launch_bounds__(256) void transpose_v_kernel(const bf16* __restrict__ qkv,
                                                          bf16* __restrict__ vt) {
  __shared__ bf16 tl[64][72];  // stride 144B keeps 16B alignment for b128 stores
  const int tid = threadIdx.x;
  const int st = blockIdx.x, bh = blockIdx.y;
  const int b = bh >> 4, h = bh & 15;
#pragma unroll
  for (int it = 0; it < 2; ++it) {
    int idx = it * 256 + tid;          // 0..511
    int sl = idx >> 3, ch = idx & 7;   // sl 0..63 (s row), ch 0..7 (d chunk)
    bf16x8 v = *(const bf16x8*)(qkv + (size_t)(b * 2048 + st * 64 + sl) * 3072 + 2048 + h * 64 + ch * 8);
    *(bf16x8*)&tl[sl][ch * 8] = v;
  }
  __syncthreads();
#pragma unroll
  for (int it = 0; it < 2; ++it) {
    int idx = it * 256 + tid;
    int d = idx >> 3, s8 = idx & 7;    // d 0..63, s chunk 0..7
    bf16x8 o;
#pragma unroll
    for (int j = 0; j < 8; ++j) o[j] = tl[s8 * 8 + j][d];
    *(bf16x8*)(vt + ((size_t)bh * 64 + d) * 2048 + st * 64 + s8 * 8) = o;
  }
}

// ---------------- causal flash attention ----------------
// Grid = 512 blocks x 512 threads (8 waves, 16 q-rows/wave), KVBLK=128.
// bh-major XCD mapping: xcd=bid&7, bh=(bid>>6)*8+xcd, x=(bid>>3)&7 -> all 8
// qt-blocks of one bh land on ONE XCD, making its K/V (512KB) L2-resident
// (8 bh x 512KB = 4MB = per-XCD L2). Block processes qt=x then qt=15-x:
// (x+1)+(16-x) = 17 uniform K-tiles. Double-buffered staging (4 loads/thread
// per tile), counted vmcnt. Swapped QK^T (mfma(K,Q)): per-lane softmax (q=c),
// in-lane PV A-frags, row-sum l via ones-MFMA directly in oacc layout.
__global__ __launch_bounds__(512, 4) void attn_kernel(const bf16* __restrict__ qkv,
                                                      const bf16* __restrict__ vt,
                                                      bf16* __restrict__ attn_out) {
  __shared__ bf16 Ks[2][128 * 64];   // [key][hd], chunk-swizzled, 16KB each
  __shared__ bf16 Vs[2][64 * 128];   // [d][key], chunk-swizzled, 16KB each
  const int tid = threadIdx.x, lane = tid & 63, wave = tid >> 6;
  const int g = lane >> 4, c = lane & 15;
  const int bid = blockIdx.x;
  const int xcd = bid & 7;
  const int x = (bid >> 3) & 7;
  const int bh = (bid >> 6) * 8 + xcd;
  const int b = bh >> 4, h = bh & 15;
  const float SCL = 0.125f * 1.4426950408889634f;  // log2(e) * scale

  bf16x8 ones;
#pragma unroll
  for (int j = 0; j < 8; ++j) ones[j] = (bf16)1.0f;

#define STAGE(KT, BUF)                                                                    \
  do {                                                                                    \
    _Pragma("unroll") for (int t2 = 0; t2 < 2; ++t2) {                                    \
      int o = t2 * 8192 + wave * 1024 + lane * 16; /* 0..16383 */                         \
      int rK = o >> 7, chK = (((o & 127) >> 4) ^ (rK & 7));                               \
      gload16((const char*)qkv +                                                          \
                  ((size_t)(b * 2048 + (KT)*128 + rK) * 3072 + 1024 + h * 64) * 2 +       \
                  (chK << 4),                                                             \
              (char*)Ks[BUF] + o);                                                        \
      int rV = o >> 8, chV = (((o & 255) >> 4) ^ (rV & 7));                               \
      gload16((const char*)vt + (((size_t)bh * 64 + rV) * 2048 + (KT)*128) * 2 +          \
                  (chV << 4),                                                             \
              (char*)Vs[BUF] + o);                                                        \
    }                                                                                     \
  } while (0)

#pragma unroll 1
  for (int ph = 0; ph < 2; ++ph) {
    const int qt = ph ? (15 - x) : x;
    const int qlow = qt * 128 + wave * 16;  // lowest q row of this wave

    bf16x8 qf[2];
#pragma unroll
    for (int kk = 0; kk < 2; ++kk) {
      size_t row = (size_t)(b * 2048 + qlow + c);
      qf[kk] = *(const bf16x8*)(qkv + row * 3072 + h * 64 + kk * 32 + g * 8);
    }

    f32x4 oacc[4] = {};
    f32x4 lacc = {};        // row-sums, oacc layout (q = qlow + 4g+i)
    float mrun = -3.0e38f;  // per-lane: q = qlow + c

    const int nkt = qt + 1;
    STAGE(0, 0);  // prologue
    for (int kt = 0; kt < nkt; ++kt) {
      const int cur = kt & 1;
      if (kt + 1 < nkt) {
        STAGE(kt + 1, cur ^ 1);
        asm volatile("s_waitcnt vmcnt(4)" ::: "memory");  // current tile landed
      } else {
        asm volatile("s_waitcnt vmcnt(0)" ::: "memory");
      }
      __builtin_amdgcn_sched_barrier(0);
      __builtin_amdgcn_s_barrier();
      __builtin_amdgcn_sched_barrier(0);
      // QK^T swapped: sc[n] holds S[key = kt*128+n*16+4g+i][q = qlow+c]
      f32x4 sc[8] = {};
      __builtin_amdgcn_s_setprio(1);
#pragma unroll
      for (int n = 0; n < 8; ++n) {
        int key = n * 16 + c;
#pragma unroll
        for (int kk = 0; kk < 2; ++kk) {
          bf16x8 kf = *(const bf16x8*)((const char*)Ks[cur] + key * 128 +
                                       (((kk * 4 + g) ^ (key & 7)) << 4));
          sc[n] = mfma16(kf, qf[kk], sc[n]);
        }
      }
      __builtin_amdgcn_s_setprio(0);
      const int q = qlow + c;
      if (kt == qt) {  // diagonal tile: causal mask
#pragma unroll
        for (int n = 0; n < 8; ++n)
#pragma unroll
          for (int i = 0; i < 4; ++i)
            sc[n][i] = ((kt * 128 + n * 16 + 4 * g + i) <= q) ? sc[n][i] : -3.0e38f;
      }
      float vmax = -3.0e38f;
#pragma unroll
      for (int n = 0; n < 8; ++n)
#pragma unroll
        for (int i = 0; i < 4; ++i) vmax = fmaxf(vmax, sc[n][i]);
      vmax = fmaxf(vmax, __shfl_xor(vmax, 16));
      vmax = fmaxf(vmax, __shfl_xor(vmax, 32));
      const float mnew = fmaxf(mrun, vmax * SCL);
      const float fs = __builtin_amdgcn_exp2f(mrun - mnew);
      mrun = mnew;
#pragma unroll
      for (int n = 0; n < 8; ++n)
#pragma unroll
        for (int i = 0; i < 4; ++i)
          sc[n][i] = __builtin_amdgcn_exp2f(fmaf(sc[n][i], SCL, -mnew));
      // broadcast fs from softmax layout (q=c) to oacc layout (q=4g+i)
#pragma unroll
      for (int i = 0; i < 4; ++i) {
        float fsb = __shfl(fs, ((lane >> 4) << 2) + i);
        lacc[i] *= fsb;
#pragma unroll
        for (int dn = 0; dn < 4; ++dn) oacc[dn][i] *= fsb;
      }
      // pack PV A-frags: key = kss*32 + (j<4 ? 4g+j : 16+4g+(j-4))
      bf16x8 pa[4];
#pragma unroll
      for (int kss = 0; kss < 4; ++kss) {
        bf16x8 t;
#pragma unroll
        for (int j = 0; j < 4; ++j) t[j] = (bf16)sc[2 * kss][j];
#pragma unroll
        for (int j = 0; j < 4; ++j) t[4 + j] = (bf16)sc[2 * kss + 1][j];
        pa[kss] = t;
      }
      // PV + row-sum via ones-MFMA; vb B-frag k = g*8+j, same kappa mapping
      __builtin_amdgcn_s_setprio(1);
#pragma unroll
      for (int kss = 0; kss < 4; ++kss) {
        lacc = mfma16(pa[kss], ones, lacc);
#pragma unroll
        for (int dn = 0; dn < 4; ++dn) {
          const int d = dn * 16 + c;
          const char* vrow = (const char*)Vs[cur] + d * 256;
          const int off = 8 * (g & 1);
          bf16x4 lo = *(const bf16x4*)(vrow + (((4 * kss + (g >> 1)) ^ (d & 7)) << 4) + off);
          bf16x4 hi = *(const bf16x4*)(vrow + (((4 * kss + 2 + (g >> 1)) ^ (d & 7)) << 4) + off);
          bf16x8 vb;
#pragma unroll
          for (int j = 0; j < 4; ++j) { vb[j] = lo[j]; vb[4 + j] = hi[j]; }
          oacc[dn] = mfma16(pa[kss], vb, oacc[dn]);
        }
      }
      __builtin_amdgcn_s_setprio(0);
      __builtin_amdgcn_sched_barrier(0);
      __builtin_amdgcn_s_barrier();  // readers done before next-tile overwrite
      __builtin_amdgcn_sched_barrier(0);
    }
    // epilogue: normalize, store bf16 [8192][1024]
#pragma unroll
    for (int i = 0; i < 4; ++i) {
      float inv = __builtin_amdgcn_rcpf(lacc[i]);
      size_t row = (size_t)(b * 2048 + qlow + 4 * g + i);
#pragma unroll
      for (int dn = 0; dn < 4; ++dn)
        attn_out[row * 1024 + h * 64 + dn * 16 + c] = (bf16)(oacc[dn][i] * inv);
    }
  }
#undef STAGE
}

// ---------------- launch ----------------
extern "C" void kernel_launch(void* const* d_in, const int* in_sizes, int n_in,
                              void* d_out, int out_size, void* d_ws, size_t ws_size,
                              hipStream_t stream) {
  const float* x  = (const float*)d_in[0];
  const float* Wq = (const float*)d_in[1];
  const float* Wk = (const float*)d_in[2];
  const float* Wv = (const float*)d_in[3];
  const float* Wo = (const float*)d_in[4];
  const float* bo = (const float*)d_in[5];
  float* out = (float*)d_out;
  char* ws = (char*)d_ws;

  bf16* Xb    = (bf16*)(ws);
  bf16* WqkvT = (bf16*)(ws + 16777216);
  bf16* WoT   = (bf16*)(ws + 23068672);
  bf16* QKV   = (bf16*)(ws + 25165824);
  bf16* VT    = (bf16*)(ws + 75497472);
  bf16* AttnO = (bf16*)(ws + 92274688);

  pack_x_kernel<<<8192, 256, 0, stream>>>(x, Xb);
  pack_wqkv_kernel<<<12288, 256, 0, stream>>>(Wq, Wk, Wv, WqkvT);
  pack_wo_kernel<<<4096, 256, 0, stream>>>(Wo, WoT);
  gemm3_kernel<false><<<1536, 512, 0, stream>>>(Xb, WqkvT, QKV, nullptr, nullptr,
                                                3072, 1024, 24);
  transpose_v_kernel<<<dim3(32, 64), 256, 0, stream>>>(QKV, VT);
  attn_kernel<<<512, 512, 0, stream>>>(QKV, VT, AttnO);
  gemm3_kernel<true><<<512, 512, 0, stream>>>(AttnO, WoT, nullptr, out, bo,
                                              1024, 1024, 8);
}

// Round 10
// 181.697 us; speedup vs baseline: 1.9511x; 1.0765x over previous
//
#include <hip/hip_runtime.h>

// B=4, S=2048, D=1024, H=16, HS=64. Full bf16-MFMA pipeline.
// Workspace layout (needs ~104 MiB):
//   Xb     @ 0         : x as bf16            [8192][1024]   16 MiB
//   WqkvT  @ 16777216  : qkv weights B^T bf16 [3072][1024]    6 MiB
//   WoT    @ 23068672  : Wo^T bf16            [1024][1024]    2 MiB
//   QKV    @ 25165824  : Q|K|V bf16           [8192][3072]   48 MiB
//   VT     @ 75497472  : V^T bf16             [64bh][64][2048] 16 MiB
//   AttnO  @ 92274688  : attention out bf16   [8192][1024]   16 MiB

typedef __bf16 bf16;
typedef bf16 bf16x8 __attribute__((ext_vector_type(8)));
typedef bf16 bf16x4 __attribute__((ext_vector_type(4)));
typedef float f32x4 __attribute__((ext_vector_type(4)));

__device__ __forceinline__ void gload16(const void* gsrc, void* ldst) {
  __builtin_amdgcn_global_load_lds(
      (const __attribute__((address_space(1))) unsigned int*)gsrc,
      (__attribute__((address_space(3))) unsigned int*)ldst, 16, 0, 0);
}

__device__ __forceinline__ f32x4 mfma16(bf16x8 a, bf16x8 b, f32x4 c) {
  return __builtin_amdgcn_mfma_f32_16x16x32_bf16(a, b, c, 0, 0, 0);
}

// ---------------- pack kernels ----------------
__global__ __launch_bounds__(256) void pack_x_kernel(const float* __restrict__ x,
                                                     bf16* __restrict__ xb) {
  int i = (blockIdx.x * 256 + threadIdx.x) * 4;  // grid sized exactly
  float4 v = *(const float4*)(x + i);
  bf16x4 o;
  o[0] = (bf16)v.x; o[1] = (bf16)v.y; o[2] = (bf16)v.z; o[3] = (bf16)v.w;
  *(bf16x4*)(xb + i) = o;
}

// WT[n][k] = W{q,k,v}[h = (n%1024)/64][k][e = n%64], n in [0,3072)
__global__ __launch_bounds__(256) void pack_wqkv_kernel(const float* __restrict__ Wq,
                                                        const float* __restrict__ Wk,
                                                        const float* __restrict__ Wv,
                                                        bf16* __restrict__ WT) {
  int idx = blockIdx.x * 256 + threadIdx.x;  // 0..3145727
  int n = idx >> 10, k = idx & 1023;
  int sel = n >> 10, nn = n & 1023;
  const float* W = (sel == 0) ? Wq : (sel == 1 ? Wk : Wv);
  int h = nn >> 6, e = nn & 63;
  WT[(size_t)n * 1024 + k] = (bf16)W[h * 65536 + k * 64 + e];
}

// WoT[n][k] = Wo[k][n]
__global__ __launch_bounds__(256) void pack_wo_kernel(const float* __restrict__ Wo,
                                                      bf16* __restrict__ WoT) {
  int idx = blockIdx.x * 256 + threadIdx.x;  // 0..1048575
  int n = idx >> 10, k = idx & 1023;
  WoT[idx] = (bf16)Wo[k * 1024 + n];
}

// ---------------- GEMM v4: C[M][N] = A[M][K] * BT[N][K]^T ----------------
// Diagnosis r7-r9: all structures converged to ~81us because per-wave 64x32
// output gives only 21.3 FLOP per LDS-read byte -> 29.8 TB/s of ds_read_b128
// at 636 TF = the practical LDS ceiling. Fix: per-wave 64x64 (32 FLOP/B) and
// minimal sync. BM=BN=128, BK=64, 256 threads (4 waves, 2x2), 2 LDS slots of
// (A 16KB + B 16KB) = 64KB -> 2 blocks/CU; grid = 64 m-tiles x NT = multiple
// of 256 -> exact dispatch rounds. Per K-tile: stage next slot at body top
// (8 gload_lds; safe: that slot's readers finished before the prior barrier),
// 16 ds_read_b128, 32 MFMA, then ONE vmcnt(0) (covered by whole body ~1000cy)
// + ONE barrier. 3-bit XOR chunk swizzle on 128B rows (2-way conflicts=free):
// LDS[r][ch] holds global chunk ch^(r&7); gload dest = waveuniform + lane*16
// (HW rule), source chunk = (lane&7)^(lane>>3). n-major-per-XCD tile mapping
// (r9-proven: A-panel 2MB + B L2-resident, FETCH 49MB).
template <bool F32OUT>
__global__ __launch_bounds__(256, 2) void gemm4_kernel(const bf16* __restrict__ A,
                                                       const bf16* __restrict__ BT,
                                                       bf16* __restrict__ Cb,
                                                       float* __restrict__ Cf,
                                                       const float* __restrict__ bias,
                                                       int N, int K) {
  __shared__ bf16 As[2][128 * 64];  // [slot][row][k], chunk-swizzled
  __shared__ bf16 Bs[2][128 * 64];
  const int tid = threadIdx.x, lane = tid & 63, wave = tid >> 6;
  const int g = lane >> 4, c = lane & 15;
  const int wr = wave >> 1, wc = wave & 1;
  const int bid = blockIdx.x;
  const int xcd = bid & 7, local = bid >> 3;
  const int m0 = (xcd * 8 + (local & 7)) * 128;
  const int n0 = (local >> 3) * 128;

  const int schunk = (lane & 7) ^ (lane >> 3);  // source k-chunk for staging

#define STAGE4(T, S)                                                      \
  do {                                                                    \
    _Pragma("unroll") for (int j = 0; j < 4; ++j) {                       \
      const int r = wave * 32 + j * 8 + (lane >> 3);                      \
      const int ldso = wave * 4096 + j * 1024 + lane * 16;                \
      gload16(A + (size_t)(m0 + r) * K + (T)*64 + schunk * 8,             \
              (char*)&As[S][0] + ldso);                                   \
      gload16(BT + (size_t)(n0 + r) * K + (T)*64 + schunk * 8,            \
              (char*)&Bs[S][0] + ldso);                                   \
    }                                                                     \
  } while (0)

  f32x4 acc[4][4] = {};
  const int nt = K >> 6;  // K-tiles of 64
  STAGE4(0, 0);
  asm volatile("s_waitcnt vmcnt(0)" ::: "memory");
  __builtin_amdgcn_sched_barrier(0);
  __builtin_amdgcn_s_barrier();
  __builtin_amdgcn_sched_barrier(0);

#pragma unroll 1
  for (int t = 0; t < nt; ++t) {
    const int s = t & 1;
    if (t + 1 < nt) STAGE4(t + 1, s ^ 1);
    bf16x8 af[4][2], bfr[4][2];
#pragma unroll
    for (int m = 0; m < 4; ++m) {
      const int row = wr * 64 + m * 16 + c;
#pragma unroll
      for (int kk = 0; kk < 2; ++kk)
        af[m][kk] = *(const bf16x8*)((const char*)&As[s][0] + row * 128 +
                                     (((kk * 4 + g) ^ (row & 7)) << 4));
    }
#pragma unroll
    for (int n = 0; n < 4; ++n) {
      const int row = wc * 64 + n * 16 + c;
#pragma unroll
      for (int kk = 0; kk < 2; ++kk)
        bfr[n][kk] = *(const bf16x8*)((const char*)&Bs[s][0] + row * 128 +
                                      (((kk * 4 + g) ^ (row & 7)) << 4));
    }
    asm volatile("s_waitcnt lgkmcnt(0)" ::: "memory");
    __builtin_amdgcn_sched_barrier(0);
    __builtin_amdgcn_s_setprio(1);
#pragma unroll
    for (int kk = 0; kk < 2; ++kk)
#pragma unroll
      for (int m = 0; m < 4; ++m)
#pragma unroll
        for (int n = 0; n < 4; ++n)
          acc[m][n] = mfma16(af[m][kk], bfr[n][kk], acc[m][n]);
    __builtin_amdgcn_s_setprio(0);
    __builtin_amdgcn_sched_barrier(0);
    if (t + 1 < nt) {
      asm volatile("s_waitcnt vmcnt(0)" ::: "memory");  // next slot landed
      __builtin_amdgcn_sched_barrier(0);
      __builtin_amdgcn_s_barrier();
      __builtin_amdgcn_sched_barrier(0);
    }
  }
#undef STAGE4
  // epilogue (r7-verified mapping)
#pragma unroll
  for (int m = 0; m < 4; ++m)
#pragma unroll
    for (int n = 0; n < 4; ++n)
#pragma unroll
      for (int i = 0; i < 4; ++i) {
        int row = m0 + wr * 64 + m * 16 + g * 4 + i;
        int col = n0 + wc * 64 + n * 16 + c;
        if (F32OUT)
          Cf[(size_t)row * N + col] = acc[m][n][i] + bias[col];
        else
          Cb[(size_t)row * N + col] = (bf16)acc[m][n][i];
      }
}

// ---------------- V transpose: VT[bh][d][s] = V[b,s,h,d] ----------------
// 64x64 tile per block; 512 bf16x8 chunks per side -> 2 iterations per thread.
__global__ __launch_bounds__(256) void transpose_v_kernel(const bf16* __restrict__ qkv,
                                                          bf16* __restrict__ vt) {
  __shared__ bf16 tl[64][72];  // stride 144B keeps 16B alignment for b128 stores
  const int tid = threadIdx.x;
  const int st = blockIdx.x, bh = blockIdx.y;
  const int b = bh >> 4, h = bh & 15;
#pragma unroll
  for (int it = 0; it < 2; ++it) {
    int idx = it * 256 + tid;          // 0..511
    int sl = idx >> 3, ch = idx & 7;   // sl 0..63 (s row), ch 0..7 (d chunk)
    bf16x8 v = *(const bf16x8*)(qkv + (size_t)(b * 2048 + st * 64 + sl) * 3072 + 2048 + h * 64 + ch * 8);
    *(bf16x8*)&tl[sl][ch * 8] = v;
  }
  __syncthreads();
#pragma unroll
  for (int it = 0; it < 2; ++it) {
    int idx = it * 256 + tid;
    int d = idx >> 3, s8 = idx & 7;    // d 0..63, s chunk 0..7
    bf16x8 o;
#pragma unroll
    for (int j = 0; j < 8; ++j) o[j] = tl[s8 * 8 + j][d];
    *(bf16x8*)(vt + ((size_t)bh * 64 + d) * 2048 + st * 64 + s8 * 8) = o;
  }
}

// ---------------- causal flash attention ----------------
// Grid = 512 blocks x 512 threads (8 waves, 16 q-rows/wave), KVBLK=128.
// bh-major XCD mapping: xcd=bid&7, bh=(bid>>6)*8+xcd, x=(bid>>3)&7 -> all 8
// qt-blocks of one bh land on ONE XCD, making its K/V (512KB) L2-resident
// (8 bh x 512KB = 4MB = per-XCD L2). Block processes qt=x then qt=15-x:
// (x+1)+(16-x) = 17 uniform K-tiles. Double-buffered staging (4 loads/thread
// per tile), counted vmcnt. Swapped QK^T (mfma(K,Q)): per-lane softmax (q=c),
// in-lane PV A-frags, row-sum l via ones-MFMA directly in oacc layout.
__global__ __launch_bounds__(512, 4) void attn_kernel(const bf16* __restrict__ qkv,
                                                      const bf16* __restrict__ vt,
                                                      bf16* __restrict__ attn_out) {
  __shared__ bf16 Ks[2][128 * 64];   // [key][hd], chunk-swizzled, 16KB each
  __shared__ bf16 Vs[2][64 * 128];   // [d][key], chunk-swizzled, 16KB each
  const int tid = threadIdx.x, lane = tid & 63, wave = tid >> 6;
  const int g = lane >> 4, c = lane & 15;
  const int bid = blockIdx.x;
  const int xcd = bid & 7;
  const int x = (bid >> 3) & 7;
  const int bh = (bid >> 6) * 8 + xcd;
  const int b = bh >> 4, h = bh & 15;
  const float SCL = 0.125f * 1.4426950408889634f;  // log2(e) * scale

  bf16x8 ones;
#pragma unroll
  for (int j = 0; j < 8; ++j) ones[j] = (bf16)1.0f;

#define STAGE(KT, BUF)                                                                    \
  do {                                                                                    \
    _Pragma("unroll") for (int t2 = 0; t2 < 2; ++t2) {                                    \
      int o = t2 * 8192 + wave * 1024 + lane * 16; /* 0..16383 */                         \
      int rK = o >> 7, chK = (((o & 127) >> 4) ^ (rK & 7));                               \
      gload16((const char*)qkv +                                                          \
                  ((size_t)(b * 2048 + (KT)*128 + rK) * 3072 + 1024 + h * 64) * 2 +       \
                  (chK << 4),                                                             \
              (char*)Ks[BUF] + o);                                                        \
      int rV = o >> 8, chV = (((o & 255) >> 4) ^ (rV & 7));                               \
      gload16((const char*)vt + (((size_t)bh * 64 + rV) * 2048 + (KT)*128) * 2 +          \
                  (chV << 4),                                                             \
              (char*)Vs[BUF] + o);                                                        \
    }                                                                                     \
  } while (0)

#pragma unroll 1
  for (int ph = 0; ph < 2; ++ph) {
    const int qt = ph ? (15 - x) : x;
    const int qlow = qt * 128 + wave * 16;  // lowest q row of this wave

    bf16x8 qf[2];
#pragma unroll
    for (int kk = 0; kk < 2; ++kk) {
      size_t row = (size_t)(b * 2048 + qlow + c);
      qf[kk] = *(const bf16x8*)(qkv + row * 3072 + h * 64 + kk * 32 + g * 8);
    }

    f32x4 oacc[4] = {};
    f32x4 lacc = {};        // row-sums, oacc layout (q = qlow + 4g+i)
    float mrun = -3.0e38f;  // per-lane: q = qlow + c

    const int nkt = qt + 1;
    STAGE(0, 0);  // prologue
    for (int kt = 0; kt < nkt; ++kt) {
      const int cur = kt & 1;
      if (kt + 1 < nkt) {
        STAGE(kt + 1, cur ^ 1);
        asm volatile("s_waitcnt vmcnt(4)" ::: "memory");  // current tile landed
      } else {
        asm volatile("s_waitcnt vmcnt(0)" ::: "memory");
      }
      __builtin_amdgcn_sched_barrier(0);
      __builtin_amdgcn_s_barrier();
      __builtin_amdgcn_sched_barrier(0);
      // QK^T swapped: sc[n] holds S[key = kt*128+n*16+4g+i][q = qlow+c]
      f32x4 sc[8] = {};
      __builtin_amdgcn_s_setprio(1);
#pragma unroll
      for (int n = 0; n < 8; ++n) {
        int key = n * 16 + c;
#pragma unroll
        for (int kk = 0; kk < 2; ++kk) {
          bf16x8 kf = *(const bf16x8*)((const char*)Ks[cur] + key * 128 +
                                       (((kk * 4 + g) ^ (key & 7)) << 4));
          sc[n] = mfma16(kf, qf[kk], sc[n]);
        }
      }
      __builtin_amdgcn_s_setprio(0);
      const int q = qlow + c;
      if (kt == qt) {  // diagonal tile: causal mask
#pragma unroll
        for (int n = 0; n < 8; ++n)
#pragma unroll
          for (int i = 0; i < 4; ++i)
            sc[n][i] = ((kt * 128 + n * 16 + 4 * g + i) <= q) ? sc[n][i] : -3.0e38f;
      }
      float vmax = -3.0e38f;
#pragma unroll
      for (int n = 0; n < 8; ++n)
#pragma unroll
        for (int i = 0; i < 4; ++i) vmax = fmaxf(vmax, sc[n][i]);
      vmax = fmaxf(vmax, __shfl_xor(vmax, 16));
      vmax = fmaxf(vmax, __shfl_xor(vmax, 32));
      const float mnew = fmaxf(mrun, vmax * SCL);
      const float fs = __builtin_amdgcn_exp2f(mrun - mnew);
      mrun = mnew;
#pragma unroll
      for (int n = 0; n < 8; ++n)
#pragma unroll
        for (int i = 0; i < 4; ++i)
          sc[n][i] = __builtin_amdgcn_exp2f(fmaf(sc[n][i], SCL, -mnew));
      // broadcast fs from softmax layout (q=c) to oacc layout (q=4g+i)
#pragma unroll
      for (int i = 0; i < 4; ++i) {
        float fsb = __shfl(fs, ((lane >> 4) << 2) + i);
        lacc[i] *= fsb;
#pragma unroll
        for (int dn = 0; dn < 4; ++dn) oacc[dn][i] *= fsb;
      }
      // pack PV A-frags: key = kss*32 + (j<4 ? 4g+j : 16+4g+(j-4))
      bf16x8 pa[4];
#pragma unroll
      for (int kss = 0; kss < 4; ++kss) {
        bf16x8 t;
#pragma unroll
        for (int j = 0; j < 4; ++j) t[j] = (bf16)sc[2 * kss][j];
#pragma unroll
        for (int j = 0; j < 4; ++j) t[4 + j] = (bf16)sc[2 * kss + 1][j];
        pa[kss] = t;
      }
      // PV + row-sum via ones-MFMA; vb B-frag k = g*8+j, same kappa mapping
      __builtin_amdgcn_s_setprio(1);
#pragma unroll
      for (int kss = 0; kss < 4; ++kss) {
        lacc = mfma16(pa[kss], ones, lacc);
#pragma unroll
        for (int dn = 0; dn < 4; ++dn) {
          const int d = dn * 16 + c;
          const char* vrow = (const char*)Vs[cur] + d * 256;
          const int off = 8 * (g & 1);
          bf16x4 lo = *(const bf16x4*)(vrow + (((4 * kss + (g >> 1)) ^ (d & 7)) << 4) + off);
          bf16x4 hi = *(const bf16x4*)(vrow + (((4 * kss + 2 + (g >> 1)) ^ (d & 7)) << 4) + off);
          bf16x8 vb;
#pragma unroll
          for (int j = 0; j < 4; ++j) { vb[j] = lo[j]; vb[4 + j] = hi[j]; }
          oacc[dn] = mfma16(pa[kss], vb, oacc[dn]);
        }
      }
      __builtin_amdgcn_s_setprio(0);
      __builtin_amdgcn_sched_barrier(0);
      __builtin_amdgcn_s_barrier();  // readers done before next-tile overwrite
      __builtin_amdgcn_sched_barrier(0);
    }
    // epilogue: normalize, store bf16 [8192][1024]
#pragma unroll
    for (int i = 0; i < 4; ++i) {
      float inv = __builtin_amdgcn_rcpf(lacc[i]);
      size_t row = (size_t)(b * 2048 + qlow + 4 * g + i);
#pragma unroll
      for (int dn = 0; dn < 4; ++dn)
        attn_out[row * 1024 + h * 64 + dn * 16 + c] = (bf16)(oacc[dn][i] * inv);
    }
  }
#undef STAGE
}

// ---------------- launch ----------------
extern "C" void kernel_launch(void* const* d_in, const int* in_sizes, int n_in,
                              void* d_out, int out_size, void* d_ws, size_t ws_size,
                              hipStream_t stream) {
  const float* x  = (const float*)d_in[0];
  const float* Wq = (const float*)d_in[1];
  const float* Wk = (const float*)d_in[2];
  const float* Wv = (const float*)d_in[3];
  const float* Wo = (const float*)d_in[4];
  const float* bo = (const float*)d_in[5];
  float* out = (float*)d_out;
  char* ws = (char*)d_ws;

  bf16* Xb    = (bf16*)(ws);
  bf16* WqkvT = (bf16*)(ws + 16777216);
  bf16* WoT   = (bf16*)(ws + 23068672);
  bf16* QKV   = (bf16*)(ws + 25165824);
  bf16* VT    = (bf16*)(ws + 75497472);
  bf16* AttnO = (bf16*)(ws + 92274688);

  pack_x_kernel<<<8192, 256, 0, stream>>>(x, Xb);
  pack_wqkv_kernel<<<12288, 256, 0, stream>>>(Wq, Wk, Wv, WqkvT);
  pack_wo_kernel<<<4096, 256, 0, stream>>>(Wo, WoT);
  gemm4_kernel<false><<<1536, 256, 0, stream>>>(Xb, WqkvT, QKV, nullptr, nullptr,
                                                3072, 1024);
  transpose_v_kernel<<<dim3(32, 64), 256, 0, stream>>>(QKV, VT);
  attn_kernel<<<512, 512, 0, stream>>>(QKV, VT, AttnO);
  gemm4_kernel<true><<<512, 256, 0, stream>>>(AttnO, WoT, nullptr, out, bo,
                                              1024, 1024);
}

// Round 11
// 172.480 us; speedup vs baseline: 2.0553x; 1.0534x over previous
//
#include <hip/hip_runtime.h>

// B=4, S=2048, D=1024, H=16, HS=64. Full bf16-MFMA pipeline.
// Workspace layout (needs ~104 MiB):
//   Xb     @ 0         : x as bf16            [8192][1024]   16 MiB
//   WqkvT  @ 16777216  : qkv weights B^T bf16 [3072][1024]    6 MiB
//   WoT    @ 23068672  : Wo^T bf16            [1024][1024]    2 MiB
//   QKV    @ 25165824  : Q|K|V bf16           [8192][3072]   48 MiB
//   VT     @ 75497472  : V^T bf16, kappa-ordered keys  [64bh][64][2048] 16 MiB
//   AttnO  @ 92274688  : attention out bf16   [8192][1024]   16 MiB

typedef __bf16 bf16;
typedef bf16 bf16x8 __attribute__((ext_vector_type(8)));
typedef bf16 bf16x4 __attribute__((ext_vector_type(4)));
typedef float f32x4 __attribute__((ext_vector_type(4)));

__device__ __forceinline__ void gload16(const void* gsrc, void* ldst) {
  __builtin_amdgcn_global_load_lds(
      (const __attribute__((address_space(1))) unsigned int*)gsrc,
      (__attribute__((address_space(3))) unsigned int*)ldst, 16, 0, 0);
}

__device__ __forceinline__ f32x4 mfma16(bf16x8 a, bf16x8 b, f32x4 c) {
  return __builtin_amdgcn_mfma_f32_16x16x32_bf16(a, b, c, 0, 0, 0);
}

// ---------------- pack kernels ----------------
__global__ __launch_bounds__(256) void pack_x_kernel(const float* __restrict__ x,
                                                     bf16* __restrict__ xb) {
  int i = (blockIdx.x * 256 + threadIdx.x) * 4;  // grid sized exactly
  float4 v = *(const float4*)(x + i);
  bf16x4 o;
  o[0] = (bf16)v.x; o[1] = (bf16)v.y; o[2] = (bf16)v.z; o[3] = (bf16)v.w;
  *(bf16x4*)(xb + i) = o;
}

// WT[n][k] = W{q,k,v}[h = (n%1024)/64][k][e = n%64], n in [0,3072)
__global__ __launch_bounds__(256) void pack_wqkv_kernel(const float* __restrict__ Wq,
                                                        const float* __restrict__ Wk,
                                                        const float* __restrict__ Wv,
                                                        bf16* __restrict__ WT) {
  int idx = blockIdx.x * 256 + threadIdx.x;  // 0..3145727
  int n = idx >> 10, k = idx & 1023;
  int sel = n >> 10, nn = n & 1023;
  const float* W = (sel == 0) ? Wq : (sel == 1 ? Wk : Wv);
  int h = nn >> 6, e = nn & 63;
  WT[(size_t)n * 1024 + k] = (bf16)W[h * 65536 + k * 64 + e];
}

// WoT[n][k] = Wo[k][n]
__global__ __launch_bounds__(256) void pack_wo_kernel(const float* __restrict__ Wo,
                                                      bf16* __restrict__ WoT) {
  int idx = blockIdx.x * 256 + threadIdx.x;  // 0..1048575
  int n = idx >> 10, k = idx & 1023;
  WoT[idx] = (bf16)Wo[k * 1024 + n];
}

// ---------------- GEMM v4: C[M][N] = A[M][K] * BT[N][K]^T ----------------
// Per-wave 64x64 (32 FLOP per LDS byte), BM=BN=128, BK=64, 256 threads
// (4 waves 2x2), 2 LDS slots (64KB) -> 2 blocks/CU. One barrier + one
// vmcnt(0) per K-tile. 3-bit XOR chunk swizzle. n-major-per-XCD mapping.
template <bool F32OUT>
__global__ __launch_bounds__(256, 2) void gemm4_kernel(const bf16* __restrict__ A,
                                                       const bf16* __restrict__ BT,
                                                       bf16* __restrict__ Cb,
                                                       float* __restrict__ Cf,
                                                       const float* __restrict__ bias,
                                                       int N, int K) {
  __shared__ bf16 As[2][128 * 64];  // [slot][row][k], chunk-swizzled
  __shared__ bf16 Bs[2][128 * 64];
  const int tid = threadIdx.x, lane = tid & 63, wave = tid >> 6;
  const int g = lane >> 4, c = lane & 15;
  const int wr = wave >> 1, wc = wave & 1;
  const int bid = blockIdx.x;
  const int xcd = bid & 7, local = bid >> 3;
  const int m0 = (xcd * 8 + (local & 7)) * 128;
  const int n0 = (local >> 3) * 128;

  const int schunk = (lane & 7) ^ (lane >> 3);  // source k-chunk for staging

#define STAGE4(T, S)                                                      \
  do {                                                                    \
    _Pragma("unroll") for (int j = 0; j < 4; ++j) {                       \
      const int r = wave * 32 + j * 8 + (lane >> 3);                      \
      const int ldso = wave * 4096 + j * 1024 + lane * 16;                \
      gload16(A + (size_t)(m0 + r) * K + (T)*64 + schunk * 8,             \
              (char*)&As[S][0] + ldso);                                   \
      gload16(BT + (size_t)(n0 + r) * K + (T)*64 + schunk * 8,            \
              (char*)&Bs[S][0] + ldso);                                   \
    }                                                                     \
  } while (0)

  f32x4 acc[4][4] = {};
  const int nt = K >> 6;  // K-tiles of 64
  STAGE4(0, 0);
  asm volatile("s_waitcnt vmcnt(0)" ::: "memory");
  __builtin_amdgcn_sched_barrier(0);
  __builtin_amdgcn_s_barrier();
  __builtin_amdgcn_sched_barrier(0);

#pragma unroll 1
  for (int t = 0; t < nt; ++t) {
    const int s = t & 1;
    if (t + 1 < nt) STAGE4(t + 1, s ^ 1);
    bf16x8 af[4][2], bfr[4][2];
#pragma unroll
    for (int m = 0; m < 4; ++m) {
      const int row = wr * 64 + m * 16 + c;
#pragma unroll
      for (int kk = 0; kk < 2; ++kk)
        af[m][kk] = *(const bf16x8*)((const char*)&As[s][0] + row * 128 +
                                     (((kk * 4 + g) ^ (row & 7)) << 4));
    }
#pragma unroll
    for (int n = 0; n < 4; ++n) {
      const int row = wc * 64 + n * 16 + c;
#pragma unroll
      for (int kk = 0; kk < 2; ++kk)
        bfr[n][kk] = *(const bf16x8*)((const char*)&Bs[s][0] + row * 128 +
                                      (((kk * 4 + g) ^ (row & 7)) << 4));
    }
    asm volatile("s_waitcnt lgkmcnt(0)" ::: "memory");
    __builtin_amdgcn_sched_barrier(0);
    __builtin_amdgcn_s_setprio(1);
#pragma unroll
    for (int kk = 0; kk < 2; ++kk)
#pragma unroll
      for (int m = 0; m < 4; ++m)
#pragma unroll
        for (int n = 0; n < 4; ++n)
          acc[m][n] = mfma16(af[m][kk], bfr[n][kk], acc[m][n]);
    __builtin_amdgcn_s_setprio(0);
    __builtin_amdgcn_sched_barrier(0);
    if (t + 1 < nt) {
      asm volatile("s_waitcnt vmcnt(0)" ::: "memory");  // next slot landed
      __builtin_amdgcn_sched_barrier(0);
      __builtin_amdgcn_s_barrier();
      __builtin_amdgcn_sched_barrier(0);
    }
  }
#undef STAGE4
  // epilogue (r7-verified mapping)
#pragma unroll
  for (int m = 0; m < 4; ++m)
#pragma unroll
    for (int n = 0; n < 4; ++n)
#pragma unroll
      for (int i = 0; i < 4; ++i) {
        int row = m0 + wr * 64 + m * 16 + g * 4 + i;
        int col = n0 + wc * 64 + n * 16 + c;
        if (F32OUT)
          Cf[(size_t)row * N + col] = acc[m][n][i] + bias[col];
        else
          Cb[(size_t)row * N + col] = (bf16)acc[m][n][i];
      }
}

// ---------------- V transpose: VT[bh][d][pos] with kappa-ordered keys ------
// Within each 32-key block, storage position p = g*8+j holds key
// kappa(p) = (j<4 ? 4g+j : 16+4g+(j-4)) -- exactly the PV B-frag order, so
// attn's V-read becomes ONE ds_read_b128 per (kss,dn) with even bank spread.
__global__ __launch_bounds__(256) void transpose_v_kernel(const bf16* __restrict__ qkv,
                                                          bf16* __restrict__ vt) {
  __shared__ bf16 tl[64][72];  // stride 144B keeps 16B alignment for b128 stores
  const int tid = threadIdx.x;
  const int st = blockIdx.x, bh = blockIdx.y;
  const int b = bh >> 4, h = bh & 15;
#pragma unroll
  for (int it = 0; it < 2; ++it) {
    int idx = it * 256 + tid;          // 0..511
    int sl = idx >> 3, ch = idx & 7;   // sl 0..63 (s row), ch 0..7 (d chunk)
    bf16x8 v = *(const bf16x8*)(qkv + (size_t)(b * 2048 + st * 64 + sl) * 3072 + 2048 + h * 64 + ch * 8);
    *(bf16x8*)&tl[sl][ch * 8] = v;
  }
  __syncthreads();
#pragma unroll
  for (int it = 0; it < 2; ++it) {
    int idx = it * 256 + tid;
    int d = idx >> 3, ch = idx & 7;    // d 0..63, output chunk 0..7 (8 keys)
    const int blk = ch >> 2, g = ch & 3;  // 32-key block, frag group
    bf16x8 o;
#pragma unroll
    for (int j = 0; j < 8; ++j) {
      int loc = (j < 4) ? (4 * g + j) : (16 + 4 * g + (j - 4));  // kappa
      o[j] = tl[blk * 32 + loc][d];
    }
    *(bf16x8*)(vt + ((size_t)bh * 64 + d) * 2048 + st * 64 + ch * 8) = o;
  }
}

// ---------------- causal flash attention ----------------
// Grid = 512 blocks x 512 threads (8 waves, 16 q-rows/wave), KVBLK=128.
// bh-major XCD mapping (K/V L2-resident per XCD). Block does qt=x then 15-x:
// 17 uniform K-tiles. Double-buffered staging, counted vmcnt. Swapped QK^T
// (mfma(K,Q)): per-lane softmax (q=c), in-lane PV A-frags, row-sum via
// ones-MFMA. Kappa-ordered VT -> single b128 V-reads, conflict-free.
// Tree-max + defer-max (T13, THR=8) cut the softmax VALU/serial chains.
__global__ __launch_bounds__(512, 4) void attn_kernel(const bf16* __restrict__ qkv,
                                                      const bf16* __restrict__ vt,
                                                      bf16* __restrict__ attn_out) {
  __shared__ bf16 Ks[2][128 * 64];   // [key][hd], chunk-swizzled, 16KB each
  __shared__ bf16 Vs[2][64 * 128];   // [d][kpos], chunk-swizzled, 16KB each
  const int tid = threadIdx.x, lane = tid & 63, wave = tid >> 6;
  const int g = lane >> 4, c = lane & 15;
  const int bid = blockIdx.x;
  const int xcd = bid & 7;
  const int x = (bid >> 3) & 7;
  const int bh = (bid >> 6) * 8 + xcd;
  const int b = bh >> 4, h = bh & 15;
  const float SCL = 0.125f * 1.4426950408889634f;  // log2(e) * scale

  bf16x8 ones;
#pragma unroll
  for (int j = 0; j < 8; ++j) ones[j] = (bf16)1.0f;

#define STAGE(KT, BUF)                                                                    \
  do {                                                                                    \
    _Pragma("unroll") for (int t2 = 0; t2 < 2; ++t2) {                                    \
      int o = t2 * 8192 + wave * 1024 + lane * 16; /* 0..16383 */                         \
      int rK = o >> 7, chK = (((o & 127) >> 4) ^ (rK & 7));                               \
      gload16((const char*)qkv +                                                          \
                  ((size_t)(b * 2048 + (KT)*128 + rK) * 3072 + 1024 + h * 64) * 2 +       \
                  (chK << 4),                                                             \
              (char*)Ks[BUF] + o);                                                        \
      int rV = o >> 8, chV = (((o & 255) >> 4) ^ (rV & 7));                               \
      gload16((const char*)vt + (((size_t)bh * 64 + rV) * 2048 + (KT)*128) * 2 +          \
                  (chV << 4),                                                             \
              (char*)Vs[BUF] + o);                                                        \
    }                                                                                     \
  } while (0)

#pragma unroll 1
  for (int ph = 0; ph < 2; ++ph) {
    const int qt = ph ? (15 - x) : x;
    const int qlow = qt * 128 + wave * 16;  // lowest q row of this wave

    bf16x8 qf[2];
#pragma unroll
    for (int kk = 0; kk < 2; ++kk) {
      size_t row = (size_t)(b * 2048 + qlow + c);
      qf[kk] = *(const bf16x8*)(qkv + row * 3072 + h * 64 + kk * 32 + g * 8);
    }

    f32x4 oacc[4] = {};
    f32x4 lacc = {};        // row-sums, oacc layout (q = qlow + 4g+i)
    float mrun = -3.0e38f;  // per-lane: q = qlow + c

    const int nkt = qt + 1;
    STAGE(0, 0);  // prologue
    for (int kt = 0; kt < nkt; ++kt) {
      const int cur = kt & 1;
      if (kt + 1 < nkt) {
        STAGE(kt + 1, cur ^ 1);
        asm volatile("s_waitcnt vmcnt(4)" ::: "memory");  // current tile landed
      } else {
        asm volatile("s_waitcnt vmcnt(0)" ::: "memory");
      }
      __builtin_amdgcn_sched_barrier(0);
      __builtin_amdgcn_s_barrier();
      __builtin_amdgcn_sched_barrier(0);
      // QK^T swapped: sc[n] holds S[key = kt*128+n*16+4g+i][q = qlow+c]
      f32x4 sc[8] = {};
      __builtin_amdgcn_s_setprio(1);
#pragma unroll
      for (int n = 0; n < 8; ++n) {
        int key = n * 16 + c;
#pragma unroll
        for (int kk = 0; kk < 2; ++kk) {
          bf16x8 kf = *(const bf16x8*)((const char*)Ks[cur] + key * 128 +
                                       (((kk * 4 + g) ^ (key & 7)) << 4));
          sc[n] = mfma16(kf, qf[kk], sc[n]);
        }
      }
      __builtin_amdgcn_s_setprio(0);
      const int q = qlow + c;
      if (kt == qt) {  // diagonal tile: causal mask
#pragma unroll
        for (int n = 0; n < 8; ++n)
#pragma unroll
          for (int i = 0; i < 4; ++i)
            sc[n][i] = ((kt * 128 + n * 16 + 4 * g + i) <= q) ? sc[n][i] : -3.0e38f;
      }
      // tree max (depth ~5 instead of a 32-deep serial chain)
      float vmax;
      {
        float a[8];
#pragma unroll
        for (int n = 0; n < 8; ++n)
          a[n] = fmaxf(fmaxf(sc[n][0], sc[n][1]), fmaxf(sc[n][2], sc[n][3]));
        float b0 = fmaxf(a[0], a[1]), b1 = fmaxf(a[2], a[3]);
        float b2 = fmaxf(a[4], a[5]), b3 = fmaxf(a[6], a[7]);
        vmax = fmaxf(fmaxf(b0, b1), fmaxf(b2, b3));
      }
      vmax = fmaxf(vmax, __shfl_xor(vmax, 16));
      vmax = fmaxf(vmax, __shfl_xor(vmax, 32));
      const float mx = vmax * SCL;
      // defer-max (T13): only rescale when the running max grew by >8 in
      // log2 domain; otherwise keep mrun (P bounded by 2^8, fp32-safe).
      if (!__all(mx <= mrun + 8.0f)) {
        const float mnew = fmaxf(mrun, mx);
        const float fs = __builtin_amdgcn_exp2f(mrun - mnew);
        mrun = mnew;
#pragma unroll
        for (int i = 0; i < 4; ++i) {
          float fsb = __shfl(fs, ((lane >> 4) << 2) + i);
          lacc[i] *= fsb;
#pragma unroll
          for (int dn = 0; dn < 4; ++dn) oacc[dn][i] *= fsb;
        }
      }
#pragma unroll
      for (int n = 0; n < 8; ++n)
#pragma unroll
        for (int i = 0; i < 4; ++i)
          sc[n][i] = __builtin_amdgcn_exp2f(fmaf(sc[n][i], SCL, -mrun));
      // pack PV A-frags: key = kss*32 + (j<4 ? 4g+j : 16+4g+(j-4))
      bf16x8 pa[4];
#pragma unroll
      for (int kss = 0; kss < 4; ++kss) {
        bf16x8 t;
#pragma unroll
        for (int j = 0; j < 4; ++j) t[j] = (bf16)sc[2 * kss][j];
#pragma unroll
        for (int j = 0; j < 4; ++j) t[4 + j] = (bf16)sc[2 * kss + 1][j];
        pa[kss] = t;
      }
      // PV + row-sum via ones-MFMA; kappa-ordered Vs -> one b128 per (kss,dn)
      __builtin_amdgcn_s_setprio(1);
#pragma unroll
      for (int kss = 0; kss < 4; ++kss) {
        lacc = mfma16(pa[kss], ones, lacc);
#pragma unroll
        for (int dn = 0; dn < 4; ++dn) {
          const int d = dn * 16 + c;
          bf16x8 vb = *(const bf16x8*)((const char*)Vs[cur] + d * 256 +
                                       (((kss * 4 + g) ^ (d & 7)) << 4));
          oacc[dn] = mfma16(pa[kss], vb, oacc[dn]);
        }
      }
      __builtin_amdgcn_s_setprio(0);
      __builtin_amdgcn_sched_barrier(0);
      __builtin_amdgcn_s_barrier();  // readers done before next-tile overwrite
      __builtin_amdgcn_sched_barrier(0);
    }
    // epilogue: normalize, store bf16 [8192][1024]
#pragma unroll
    for (int i = 0; i < 4; ++i) {
      float inv = __builtin_amdgcn_rcpf(lacc[i]);
      size_t row = (size_t)(b * 2048 + qlow + 4 * g + i);
#pragma unroll
      for (int dn = 0; dn < 4; ++dn)
        attn_out[row * 1024 + h * 64 + dn * 16 + c] = (bf16)(oacc[dn][i] * inv);
    }
  }
#undef STAGE
}

// ---------------- launch ----------------
extern "C" void kernel_launch(void* const* d_in, const int* in_sizes, int n_in,
                              void* d_out, int out_size, void* d_ws, size_t ws_size,
                              hipStream_t stream) {
  const float* x  = (const float*)d_in[0];
  const float* Wq = (const float*)d_in[1];
  const float* Wk = (const float*)d_in[2];
  const float* Wv = (const float*)d_in[3];
  const float* Wo = (const float*)d_in[4];
  const float* bo = (const float*)d_in[5];
  float* out = (float*)d_out;
  char* ws = (char*)d_ws;

  bf16* Xb    = (bf16*)(ws);
  bf16* WqkvT = (bf16*)(ws + 16777216);
  bf16* WoT   = (bf16*)(ws + 23068672);
  bf16* QKV   = (bf16*)(ws + 25165824);
  bf16* VT    = (bf16*)(ws + 75497472);
  bf16* AttnO = (bf16*)(ws + 92274688);

  pack_x_kernel<<<8192, 256, 0, stream>>>(x, Xb);
  pack_wqkv_kernel<<<12288, 256, 0, stream>>>(Wq, Wk, Wv, WqkvT);
  pack_wo_kernel<<<4096, 256, 0, stream>>>(Wo, WoT);
  gemm4_kernel<false><<<1536, 256, 0, stream>>>(Xb, WqkvT, QKV, nullptr, nullptr,
                                                3072, 1024);
  transpose_v_kernel<<<dim3(32, 64), 256, 0, stream>>>(QKV, VT);
  attn_kernel<<<512, 512, 0, stream>>>(QKV, VT, AttnO);
  gemm4_kernel<true><<<512, 256, 0, stream>>>(AttnO, WoT, nullptr, out, bo,
                                              1024, 1024);
}